// Round 1
// baseline (171.006 us; speedup 1.0000x reference)
//
#include <hip/hip_runtime.h>
#include <math.h>

// Causal MHA forward, B=2 H=16 S=2048 D=64, fp32 in/out, bf16 MFMA compute.
// Round 6: LDS-traffic cut.
//  - V fragments read DIRECTLY from L2-resident Vt (bf16, pre-transposed) --
//    no Vs staging, no Vs ds_reads.
//  - Swapped QK^T (mfma(K,Q)) puts each q-row's P in one lane; P->A-frag
//    transpose done in-register via v_cvt_pk_bf16_f32 + permlane16/32_swap.
//    Ps LDS buffer, 16 ds_write_b16 + 2 ds_read_b128 + lgkm drain per tile all
//    deleted.
//  - LDS now 16 KB (double-buffered K only), conflict-free xor-swizzle kept.

#define S_LEN   2048
#define D_HEAD  64
#define SCALE_L2E 0.18033688011112042f   // (1/sqrt(D)) * log2(e)
#define FIXM    8.0f                     // fixed softmax offset (exponent-safe)

using bf16x8 = __attribute__((ext_vector_type(8))) short;
using f32x4  = __attribute__((ext_vector_type(4))) float;
using uint4v = __attribute__((ext_vector_type(4))) unsigned int;

__device__ __forceinline__ unsigned int rnd_bf(float f) {
  return __float_as_uint(f) + 0x8000u;
}
__device__ __forceinline__ unsigned short f2bf(float f) {
  return (unsigned short)(rnd_bf(f) >> 16);
}

// async global->LDS, 16B per lane; LDS dest = uniform base + lane*16
__device__ __forceinline__ void gl_lds16(const unsigned short* g, unsigned short* l) {
  __builtin_amdgcn_global_load_lds(
      (const __attribute__((address_space(1))) unsigned int*)g,
      (__attribute__((address_space(3))) unsigned int*)l, 16, 0, 0);
}

// pack two f32 -> one dword of 2 x bf16 (lo = first arg)
__device__ __forceinline__ unsigned int cvtpk_bf16(float lo, float hi) {
  unsigned int r;
  asm("v_cvt_pk_bf16_f32 %0, %1, %2" : "=v"(r) : "v"(lo), "v"(hi));
  return r;
}
// a' = [a.lo32, b.lo32]; b' = [a.hi32, b.hi32]
__device__ __forceinline__ void swap32(unsigned int& a, unsigned int& b) {
  asm("v_permlane32_swap_b32 %0, %1" : "+v"(a), "+v"(b));
}
// rows = 16-lane groups: a' = [a.r0, b.r0, a.r2, b.r2]; b' = [a.r1, b.r1, a.r3, b.r3]
__device__ __forceinline__ void swap16(unsigned int& a, unsigned int& b) {
  asm("v_permlane16_swap_b32 %0, %1" : "+v"(a), "+v"(b));
}

// DPP cross-lane 16-wide sum (fa_fb epilogue only)
template <int CTRL>
__device__ __forceinline__ float dppf(float x) {
  return __builtin_bit_cast(float,
      __builtin_amdgcn_update_dpp(0, __builtin_bit_cast(int, x), CTRL, 0xF, 0xF, false));
}
__device__ __forceinline__ float rowsum16(float x) {
  x += dppf<0xB1>(x);
  x += dppf<0x4E>(x);
  x += dppf<0x124>(x);
  x += dppf<0x128>(x);
  return x;
}

// ---------------- pre-pass: K -> bf16 [bh][s][d]; V -> bf16 transposed [bh][d][s]
__global__ __launch_bounds__(256, 4)
void prep(const float* __restrict__ Kg, const float* __restrict__ Vg,
          unsigned short* __restrict__ Kb, unsigned short* __restrict__ Vt)
{
  __shared__ __align__(16) unsigned short Lt[64][72];
  const int j = blockIdx.x, t = threadIdx.x;
  const int bh = j >> 4, seg = j & 15;
  const size_t base = (size_t)bh * (S_LEN * D_HEAD) + (size_t)seg * 128 * D_HEAD;
#pragma unroll
  for (int i = 0; i < 8; ++i) {
    const size_t idx = base + i * 1024 + t * 4;
    const f32x4 v = *(const f32x4*)(Kg + idx);
    uint2 pk;
    pk.x = (rnd_bf(v[1]) & 0xFFFF0000u) | (rnd_bf(v[0]) >> 16);
    pk.y = (rnd_bf(v[3]) & 0xFFFF0000u) | (rnd_bf(v[2]) >> 16);
    *(uint2*)(Kb + idx) = pk;
  }
  for (int h = 0; h < 2; ++h) {
    const int s0 = seg * 128 + h * 64;
    __syncthreads();
#pragma unroll
    for (int pp = 0; pp < 4; ++pp) {
      const int r = t >> 2;
      const int d0 = (t & 3) * 4 + pp * 16;
      const f32x4 v = *(const f32x4*)(Vg + (size_t)bh * (S_LEN * D_HEAD)
                                         + (size_t)(s0 + r) * D_HEAD + d0);
#pragma unroll
      for (int e = 0; e < 4; ++e) Lt[d0 + e][r] = f2bf(v[e]);
    }
    __syncthreads();
#pragma unroll
    for (int q = 0; q < 2; ++q) {
      const int d = t >> 2, ch = (t & 3) + 4 * q;
      *(uint4*)(Vt + (size_t)(bh * 64 + d) * S_LEN + s0 + ch * 8) =
          *(const uint4*)&Lt[d][ch * 8];
    }
  }
}

// ---------------- main attention kernel
__global__ __launch_bounds__(256, 4)
void fa(const float* __restrict__ Qg, const unsigned short* __restrict__ Kb,
        const unsigned short* __restrict__ Vt, float* __restrict__ Og)
{
  __shared__ unsigned short Ks[2][64][64];   // 16 KB total

  const int id = blockIdx.x;            // 1024 blocks
  const int bh = id & 31;               // id%8 == bh%8 -> head-local XCD L2 reuse
  const int p  = id >> 5;               // strip pair 0..31

  const int t    = threadIdx.x;
  const int w    = t >> 6;
  const int lane = t & 63;
  const int c    = lane & 15;
  const int quad = lane >> 4;

  const float* __restrict__ Qb = Qg + (size_t)bh * (S_LEN * D_HEAD);
  float* __restrict__ Ob = Og + (size_t)bh * (S_LEN * D_HEAD);

  // waves 0,1 -> low strip rows 32p+16wv; waves 2,3 -> mirrored high strip
  const int wv   = w & 1;
  const int row0 = (w >= 2) ? (S_LEN - 32 * (p + 1) + 16 * wv)
                            : (32 * p + 16 * wv);
  const int ktdiag = row0 >> 6;                 // active for kt<=ktdiag, mask at ==
  const int ktmax  = (S_LEN - 1 - 32 * p) >> 6; // block loop bound (hi diag)

  // ---- Q fragment (serves as B-operand of swapped QK^T), pre-scaled, bf16
  // layout: elem j of qa[h] = Q[row0+c][32h + quad*8 + j]
  bf16x8 qa[2];
  {
    const float* qp = Qb + (size_t)(row0 + c) * D_HEAD + quad * 8;
#pragma unroll
    for (int h = 0; h < 2; ++h) {
      f32x4 a0 = *(const f32x4*)(qp + 32 * h);
      f32x4 a1 = *(const f32x4*)(qp + 32 * h + 4);
#pragma unroll
      for (int j = 0; j < 4; ++j) {
        qa[h][j]     = (short)f2bf(a0[j] * SCALE_L2E);
        qa[h][4 + j] = (short)f2bf(a1[j] * SCALE_L2E);
      }
    }
  }

  // ---- loop-invariant swizzled LDS offsets for K fragments (shorts)
  int fOff[4][2];
#pragma unroll
  for (int ci = 0; ci < 4; ++ci)
#pragma unroll
    for (int h = 0; h < 2; ++h)
      fOff[ci][h] = ((ci * 16 + c) << 6) + (((h * 4 + quad) ^ (c & 7)) << 3);

  // V fragment base (direct global reads; L2-resident)
  const unsigned short* vbase = Vt + (((size_t)(bh * 64 + c)) << 11) + quad * 8;

  f32x4 oa[4];
#pragma unroll
  for (int i = 0; i < 4; ++i) oa[i] = (f32x4){0.f, 0.f, 0.f, 0.f};
  float ls = 0.f;   // row sum for q-row row0+c (partial: this lane's 16 cols/tile)

  // per-wave staging: 2 instrs K, 16 rows each wave
  const int rl = lane >> 3;
  const int jj = (lane & 7) ^ rl;
  auto stage = [&](int kt, int buf) {
#pragma unroll
    for (int n = 0; n < 2; ++n) {
      const int row = w * 16 + n * 8 + rl;
      gl_lds16(Kb + (((size_t)(bh * S_LEN + kt * 64 + row)) << 6) + jj * 8,
               &Ks[buf][w * 16 + n * 8][0]);
    }
  };

  stage(0, 0);
  for (int kt = 0; kt <= ktmax; ++kt) {
    const int cur = kt & 1;
    __syncthreads();                       // drains prefetch + prior LDS reads
    if (kt < ktmax) stage(kt + 1, cur ^ 1);

    if (kt <= ktdiag) {
      // ---- V frags direct from global (issued early; S-phase hides latency)
      bf16x8 vf[4][2];
      {
        const unsigned short* vb = vbase + kt * 64;
#pragma unroll
        for (int ci = 0; ci < 4; ++ci) {
          vf[ci][0] = *(const bf16x8*)(vb + ((size_t)ci << 15));
          vf[ci][1] = *(const bf16x8*)(vb + ((size_t)ci << 15) + 32);
        }
      }
      // ---- K frags from LDS
      const unsigned short* ksc = &Ks[cur][0][0];
      bf16x8 kf[4][2];
#pragma unroll
      for (int ci = 0; ci < 4; ++ci)
#pragma unroll
        for (int h = 0; h < 2; ++h)
          kf[ci][h] = *(const bf16x8*)(ksc + fOff[ci][h]);

      // ---- S^T = K Q^T (swapped). C: row=quad*4+r -> kcol ci*16+quad*4+r,
      //                               col=c        -> q-row row0+c
      f32x4 sc[4];
#pragma unroll
      for (int ci = 0; ci < 4; ++ci) {
        f32x4 acc = (f32x4){-FIXM, -FIXM, -FIXM, -FIXM};
        acc = __builtin_amdgcn_mfma_f32_16x16x32_bf16(kf[ci][0], qa[0], acc, 0, 0, 0);
        acc = __builtin_amdgcn_mfma_f32_16x16x32_bf16(kf[ci][1], qa[1], acc, 0, 0, 0);
        sc[ci] = acc;
      }
      if (kt == ktdiag) {   // diagonal tile mask
        const int grow = row0 + c;
#pragma unroll
        for (int ci = 0; ci < 4; ++ci)
#pragma unroll
          for (int r = 0; r < 4; ++r)
            if (kt * 64 + ci * 16 + quad * 4 + r > grow) sc[ci][r] = -1e30f;
      }
      // ---- softmax (fixed max) + pack to bf16 words
      unsigned int Wt[4][2];
#pragma unroll
      for (int ci = 0; ci < 4; ++ci) {
#pragma unroll
        for (int r = 0; r < 4; ++r)
          sc[ci][r] = __builtin_amdgcn_exp2f(sc[ci][r]);
        ls += (sc[ci][0] + sc[ci][1]) + (sc[ci][2] + sc[ci][3]);
        Wt[ci][0] = cvtpk_bf16(sc[ci][0], sc[ci][1]);
        Wt[ci][1] = cvtpk_bf16(sc[ci][2], sc[ci][3]);
      }
      // ---- in-register P transpose: word (srcQuad s, block b) -> quad 2(b&1)+(s>>1)
      // one 32-swap + one 16-swap yields both even- and odd-source outputs.
      unsigned int a00 = Wt[0][0], a02 = Wt[1][0]; swap32(a00, a02); swap16(a00, a02);
      unsigned int a01 = Wt[0][1], a03 = Wt[1][1]; swap32(a01, a03); swap16(a01, a03);
      unsigned int a10 = Wt[2][0], a12 = Wt[3][0]; swap32(a10, a12); swap16(a10, a12);
      unsigned int a11 = Wt[2][1], a13 = Wt[3][1]; swap32(a11, a13); swap16(a11, a13);
      const bf16x8 pa0 = __builtin_bit_cast(bf16x8, (uint4v){a00, a01, a02, a03});
      const bf16x8 pa1 = __builtin_bit_cast(bf16x8, (uint4v){a10, a11, a12, a13});

      // ---- O += P V
#pragma unroll
      for (int ci = 0; ci < 4; ++ci) {
        oa[ci] = __builtin_amdgcn_mfma_f32_16x16x32_bf16(pa0, vf[ci][0], oa[ci], 0, 0, 0);
        oa[ci] = __builtin_amdgcn_mfma_f32_16x16x32_bf16(pa1, vf[ci][1], oa[ci], 0, 0, 0);
      }
    }
  }

  // ---- epilogue: quad-reduce row sums, redistribute, O/l, fp32 stores
  {
    float tot = ls;                     // lane (c,quad): partial for row row0+c
    tot += __shfl_xor(tot, 16, 64);
    tot += __shfl_xor(tot, 32, 64);     // full sum for row row0+c in all 4 copies
    float inv[4];
#pragma unroll
    for (int r = 0; r < 4; ++r)
      inv[r] = 1.0f / __shfl(tot, quad * 4 + r, 64);  // row row0+quad*4+r
#pragma unroll
    for (int ci = 0; ci < 4; ++ci)
#pragma unroll
      for (int r = 0; r < 4; ++r)
        Ob[(size_t)(row0 + quad * 4 + r) * D_HEAD + ci * 16 + c] = oa[ci][r] * inv[r];
  }
}

// ---------------- fallback (fp32 inputs direct) if ws too small
__global__ __launch_bounds__(256, 4)
void fa_fb(const float* __restrict__ Qg, const float* __restrict__ Kg,
           const float* __restrict__ Vg, float* __restrict__ Og)
{
  __shared__ __align__(16) unsigned short Ksh[64][72];
  __shared__ __align__(16) unsigned short Vsh[64][72];
  __shared__ __align__(16) unsigned short Psh[4][16][72];
  const int id = blockIdx.x;
  const int bh = id & 31;
  const int p  = id >> 5;
  const int t    = threadIdx.x;
  const int w    = t >> 6;
  const int lane = t & 63;
  const int c    = lane & 15;
  const int quad = lane >> 4;
  const size_t base = (size_t)bh * (S_LEN * D_HEAD);
  const float* __restrict__ Qb = Qg + base;
  const float* __restrict__ Kb = Kg + base;
  const float* __restrict__ Vb = Vg + base;
  float* __restrict__ Ob = Og + base;
  const int wv   = w & 1;
  const int row0 = (w >= 2) ? (S_LEN - 32 * (p + 1) + 16 * wv) : (32 * p + 16 * wv);
  const int ktdiag = row0 >> 6;
  const int ktmax  = (S_LEN - 1 - 32 * p) >> 6;
  bf16x8 qa[2];
  {
    const float* qp = Qb + (size_t)(row0 + c) * D_HEAD + quad * 8;
#pragma unroll
    for (int h = 0; h < 2; ++h) {
      f32x4 a0 = *(const f32x4*)(qp + 32 * h);
      f32x4 a1 = *(const f32x4*)(qp + 32 * h + 4);
#pragma unroll
      for (int j = 0; j < 4; ++j) {
        qa[h][j]     = (short)f2bf(a0[j] * SCALE_L2E);
        qa[h][4 + j] = (short)f2bf(a1[j] * SCALE_L2E);
      }
    }
  }
  f32x4 oa[4];
  float ls[4];
#pragma unroll
  for (int i = 0; i < 4; ++i) {
    oa[i] = (f32x4){0.f, 0.f, 0.f, 0.f};
    ls[i] = 0.f;
  }
  for (int kt = 0; kt <= ktmax; ++kt) {
    __syncthreads();
    {
      const int cp = t & 15;
      const int rg = t >> 4;
      const int col0 = cp * 4;
      const int sw = (cp >> 2) << 3;
#pragma unroll
      for (int i = 0; i < 4; ++i) {
        const int row = i * 16 + rg;
        const size_t goff = (size_t)(kt * 64 + row) * D_HEAD + col0;
        const f32x4 kv = *(const f32x4*)(Kb + goff);
        const f32x4 vv = *(const f32x4*)(Vb + goff);
        const unsigned int k01 = (rnd_bf(kv[1]) & 0xFFFF0000u) | (rnd_bf(kv[0]) >> 16);
        const unsigned int k23 = (rnd_bf(kv[3]) & 0xFFFF0000u) | (rnd_bf(kv[2]) >> 16);
        *(uint2*)&Ksh[row][col0] = make_uint2(k01, k23);
        const int kz = row ^ sw;
#pragma unroll
        for (int e = 0; e < 4; ++e)
          Vsh[col0 + e][kz] = f2bf(vv[e]);
      }
    }
    __syncthreads();
    if (kt <= ktdiag) {
      bf16x8 kf[4][2], vf[4][2];
#pragma unroll
      for (int ci = 0; ci < 4; ++ci) {
        kf[ci][0] = *(const bf16x8*)&Ksh[ci * 16 + c][quad * 8];
        kf[ci][1] = *(const bf16x8*)&Ksh[ci * 16 + c][32 + quad * 8];
        vf[ci][0] = *(const bf16x8*)&Vsh[ci * 16 + c][(quad ^ ci) * 8];
        vf[ci][1] = *(const bf16x8*)&Vsh[ci * 16 + c][32 + ((quad ^ ci) * 8)];
      }
      f32x4 sc[4];
#pragma unroll
      for (int ci = 0; ci < 4; ++ci) {
        f32x4 acc = (f32x4){-FIXM, -FIXM, -FIXM, -FIXM};
        acc = __builtin_amdgcn_mfma_f32_16x16x32_bf16(qa[0], kf[ci][0], acc, 0, 0, 0);
        acc = __builtin_amdgcn_mfma_f32_16x16x32_bf16(qa[1], kf[ci][1], acc, 0, 0, 0);
        sc[ci] = acc;
      }
      if (kt == ktdiag) {
#pragma unroll
        for (int ci = 0; ci < 4; ++ci) {
          const int gcol = kt * 64 + ci * 16 + c;
#pragma unroll
          for (int r = 0; r < 4; ++r)
            if (gcol > row0 + quad * 4 + r) sc[ci][r] = -1e30f;
        }
      }
#pragma unroll
      for (int ci = 0; ci < 4; ++ci)
#pragma unroll
        for (int r = 0; r < 4; ++r)
          sc[ci][r] = __builtin_amdgcn_exp2f(sc[ci][r]);
#pragma unroll
      for (int r = 0; r < 4; ++r)
        ls[r] += (sc[0][r] + sc[1][r]) + (sc[2][r] + sc[3][r]);
#pragma unroll
      for (int ci = 0; ci < 4; ++ci)
#pragma unroll
        for (int r = 0; r < 4; ++r) {
          const int prow = quad * 4 + r;
          Psh[w][prow][(ci * 16 + c) ^ ((prow >> 3) << 3)] = f2bf(sc[ci][r]);
        }
      const int px = (c >> 3) << 3;
      const bf16x8 pa0 = *(const bf16x8*)&Psh[w][c][(quad * 8) ^ px];
      const bf16x8 pa1 = *(const bf16x8*)&Psh[w][c][((32 + quad * 8)) ^ px];
#pragma unroll
      for (int ci = 0; ci < 4; ++ci) {
        oa[ci] = __builtin_amdgcn_mfma_f32_16x16x32_bf16(pa0, vf[ci][0], oa[ci], 0, 0, 0);
        oa[ci] = __builtin_amdgcn_mfma_f32_16x16x32_bf16(pa1, vf[ci][1], oa[ci], 0, 0, 0);
      }
    }
  }
  {
    float inv[4];
#pragma unroll
    for (int r = 0; r < 4; ++r) inv[r] = 1.0f / rowsum16(ls[r]);
#pragma unroll
    for (int ci = 0; ci < 4; ++ci)
#pragma unroll
      for (int r = 0; r < 4; ++r)
        Ob[(size_t)(row0 + quad * 4 + r) * D_HEAD + ci * 16 + c] = oa[ci][r] * inv[r];
  }
}

extern "C" void kernel_launch(void* const* d_in, const int* in_sizes, int n_in,
                              void* d_out, int out_size, void* d_ws, size_t ws_size,
                              hipStream_t stream) {
  (void)in_sizes; (void)n_in; (void)out_size;
  const float* Q = (const float*)d_in[0];
  const float* K = (const float*)d_in[1];
  const float* V = (const float*)d_in[2];
  float* O = (float*)d_out;   // d_in[3] (causal mask) computed analytically
  const size_t NEED = 2ull * 32 * S_LEN * D_HEAD * 2;  // Kb16 + Vt = 16 MB
  if (ws_size >= NEED) {
    unsigned short* Kb = (unsigned short*)d_ws;
    unsigned short* Vt = Kb + (size_t)32 * S_LEN * D_HEAD;
    prep<<<dim3(512), dim3(256), 0, stream>>>(K, V, Kb, Vt);
    fa<<<dim3(1024), dim3(256), 0, stream>>>(Q, Kb, Vt, O);
  } else {
    fa_fb<<<dim3(1024), dim3(256), 0, stream>>>(Q, K, V, O);
  }
}

// Round 2
// 141.203 us; speedup vs baseline: 1.2111x; 1.2111x over previous
//
#include <hip/hip_runtime.h>
#include <math.h>

// Causal MHA forward, B=2 H=16 S=2048 D=64, fp32 in/out, bf16 MFMA compute.
// Round 7: revert V to LDS staging (round-6's direct-L2 V read regressed:
// uncovered L2 latency on the per-tile critical path). Keep the verified
// swapped-QK^T + in-register P transpose (cvt_pk_bf16 + permlane swaps).
// New: 32 Q-rows per wave (two 16-row M-blocks) -> 16 ds_read_b128 per tile
// amortized over 32 MFMA instead of 16, halving LDS-read cost per FLOP.
// 128-thread blocks (2 waves: low strip + mirrored high strip), 1024 blocks,
// LDS 32 KB -> 4 blocks/CU.

#define S_LEN   2048
#define D_HEAD  64
#define SCALE_L2E 0.18033688011112042f   // (1/sqrt(D)) * log2(e)
#define FIXM    8.0f                     // fixed softmax offset (exponent-safe)

using bf16x8 = __attribute__((ext_vector_type(8))) short;
using f32x4  = __attribute__((ext_vector_type(4))) float;
using uint4v = __attribute__((ext_vector_type(4))) unsigned int;

__device__ __forceinline__ unsigned int rnd_bf(float f) {
  return __float_as_uint(f) + 0x8000u;
}
__device__ __forceinline__ unsigned short f2bf(float f) {
  return (unsigned short)(rnd_bf(f) >> 16);
}

// async global->LDS, 16B per lane; LDS dest = uniform base + lane*16
__device__ __forceinline__ void gl_lds16(const unsigned short* g, unsigned short* l) {
  __builtin_amdgcn_global_load_lds(
      (const __attribute__((address_space(1))) unsigned int*)g,
      (__attribute__((address_space(3))) unsigned int*)l, 16, 0, 0);
}

// pack two f32 -> one dword of 2 x bf16 (lo = first arg)
__device__ __forceinline__ unsigned int cvtpk_bf16(float lo, float hi) {
  unsigned int r;
  asm("v_cvt_pk_bf16_f32 %0, %1, %2" : "=v"(r) : "v"(lo), "v"(hi));
  return r;
}
// a' = [a.lo32, b.lo32]; b' = [a.hi32, b.hi32]
__device__ __forceinline__ void swap32(unsigned int& a, unsigned int& b) {
  asm("v_permlane32_swap_b32 %0, %1" : "+v"(a), "+v"(b));
}
// rows = 16-lane groups: a' = [a.r0, b.r0, a.r2, b.r2]; b' = [a.r1, b.r1, a.r3, b.r3]
__device__ __forceinline__ void swap16(unsigned int& a, unsigned int& b) {
  asm("v_permlane16_swap_b32 %0, %1" : "+v"(a), "+v"(b));
}

// DPP cross-lane 16-wide sum (fa_fb epilogue only)
template <int CTRL>
__device__ __forceinline__ float dppf(float x) {
  return __builtin_bit_cast(float,
      __builtin_amdgcn_update_dpp(0, __builtin_bit_cast(int, x), CTRL, 0xF, 0xF, false));
}
__device__ __forceinline__ float rowsum16(float x) {
  x += dppf<0xB1>(x);
  x += dppf<0x4E>(x);
  x += dppf<0x124>(x);
  x += dppf<0x128>(x);
  return x;
}

// ---------------- pre-pass: K -> bf16 [bh][s][d]; V -> bf16 transposed [bh][d][s]
__global__ __launch_bounds__(256, 4)
void prep(const float* __restrict__ Kg, const float* __restrict__ Vg,
          unsigned short* __restrict__ Kb, unsigned short* __restrict__ Vt)
{
  __shared__ __align__(16) unsigned short Lt[64][72];
  const int j = blockIdx.x, t = threadIdx.x;
  const int bh = j >> 4, seg = j & 15;
  const size_t base = (size_t)bh * (S_LEN * D_HEAD) + (size_t)seg * 128 * D_HEAD;
#pragma unroll
  for (int i = 0; i < 8; ++i) {
    const size_t idx = base + i * 1024 + t * 4;
    const f32x4 v = *(const f32x4*)(Kg + idx);
    uint2 pk;
    pk.x = (rnd_bf(v[1]) & 0xFFFF0000u) | (rnd_bf(v[0]) >> 16);
    pk.y = (rnd_bf(v[3]) & 0xFFFF0000u) | (rnd_bf(v[2]) >> 16);
    *(uint2*)(Kb + idx) = pk;
  }
  for (int h = 0; h < 2; ++h) {
    const int s0 = seg * 128 + h * 64;
    __syncthreads();
#pragma unroll
    for (int pp = 0; pp < 4; ++pp) {
      const int r = t >> 2;
      const int d0 = (t & 3) * 4 + pp * 16;
      const f32x4 v = *(const f32x4*)(Vg + (size_t)bh * (S_LEN * D_HEAD)
                                         + (size_t)(s0 + r) * D_HEAD + d0);
#pragma unroll
      for (int e = 0; e < 4; ++e) Lt[d0 + e][r] = f2bf(v[e]);
    }
    __syncthreads();
#pragma unroll
    for (int q = 0; q < 2; ++q) {
      const int d = t >> 2, ch = (t & 3) + 4 * q;
      *(uint4*)(Vt + (size_t)(bh * 64 + d) * S_LEN + s0 + ch * 8) =
          *(const uint4*)&Lt[d][ch * 8];
    }
  }
}

// ---------------- main attention kernel: 2 waves x 32 rows, mirrored strips
__global__ __launch_bounds__(128, 2)
void fa(const float* __restrict__ Qg, const unsigned short* __restrict__ Kb,
        const unsigned short* __restrict__ Vt, float* __restrict__ Og)
{
  __shared__ unsigned short Ks[2][64][64];   // 16 KB
  __shared__ unsigned short Vs[2][64][64];   // 16 KB -> 32 KB total, 4 blk/CU

  const int id = blockIdx.x;            // 1024 blocks
  const int bh = id & 31;               // id%8 == bh%8 -> head-local XCD L2 reuse
  const int p  = id >> 5;               // strip pair 0..31

  const int t    = threadIdx.x;         // 0..127
  const int w    = t >> 6;              // wave 0: low strip, wave 1: high strip
  const int lane = t & 63;
  const int c    = lane & 15;
  const int quad = lane >> 4;

  const float* __restrict__ Qb = Qg + (size_t)bh * (S_LEN * D_HEAD);
  float* __restrict__ Ob = Og + (size_t)bh * (S_LEN * D_HEAD);

  const int row0 = (w == 1) ? (S_LEN - 32 * (p + 1)) : (32 * p);  // 32 rows/wave
  const int ktdiag = (row0 + 31) >> 6;          // active for kt<=ktdiag, mask at ==
  const int ktmax  = (S_LEN - 1 - 32 * p) >> 6; // block loop bound (hi diag)

  // ---- Q fragments (B-operand of swapped QK^T), two row-blocks, pre-scaled
  // qa[rb][h] elem j = Q[row0+rb*16+c][32h + quad*8 + j] * scale
  bf16x8 qa[2][2];
#pragma unroll
  for (int rb = 0; rb < 2; ++rb) {
    const float* qp = Qb + (size_t)(row0 + rb * 16 + c) * D_HEAD + quad * 8;
#pragma unroll
    for (int h = 0; h < 2; ++h) {
      f32x4 a0 = *(const f32x4*)(qp + 32 * h);
      f32x4 a1 = *(const f32x4*)(qp + 32 * h + 4);
#pragma unroll
      for (int j = 0; j < 4; ++j) {
        qa[rb][h][j]     = (short)f2bf(a0[j] * SCALE_L2E);
        qa[rb][h][4 + j] = (short)f2bf(a1[j] * SCALE_L2E);
      }
    }
  }

  // ---- loop-invariant swizzled LDS offsets (shorts); same for K and V tiles
  int fOff[4][2];
#pragma unroll
  for (int ci = 0; ci < 4; ++ci)
#pragma unroll
    for (int h = 0; h < 2; ++h)
      fOff[ci][h] = ((ci * 16 + c) << 6) + (((h * 4 + quad) ^ (c & 7)) << 3);

  f32x4 oa[2][4];
  float ls[2] = {0.f, 0.f};
#pragma unroll
  for (int rb = 0; rb < 2; ++rb)
#pragma unroll
    for (int i = 0; i < 4; ++i) oa[rb][i] = (f32x4){0.f, 0.f, 0.f, 0.f};

  // per-wave staging: 4 instrs K + 4 instrs V, 32 rows each wave
  const int rl = lane >> 3;
  const int jj = (lane & 7) ^ rl;
  auto stage = [&](int kt, int buf) {
#pragma unroll
    for (int n = 0; n < 4; ++n) {
      const int row = w * 32 + n * 8 + rl;
      gl_lds16(Kb + (((size_t)(bh * S_LEN + kt * 64 + row)) << 6) + jj * 8,
               &Ks[buf][w * 32 + n * 8][0]);
      gl_lds16(Vt + (((size_t)(bh * 64 + row)) << 11) + kt * 64 + jj * 8,
               &Vs[buf][w * 32 + n * 8][0]);
    }
  };

  stage(0, 0);
  for (int kt = 0; kt <= ktmax; ++kt) {
    const int cur = kt & 1;
    __syncthreads();                       // drains prefetch + prior LDS reads
    if (kt < ktmax) stage(kt + 1, cur ^ 1);

    if (kt <= ktdiag) {
      const unsigned short* ksc = &Ks[cur][0][0];
      const unsigned short* vsc = &Vs[cur][0][0];
      bf16x8 kf[4][2], vf[4][2];
#pragma unroll
      for (int ci = 0; ci < 4; ++ci)
#pragma unroll
        for (int h = 0; h < 2; ++h) {
          kf[ci][h] = *(const bf16x8*)(ksc + fOff[ci][h]);
          vf[ci][h] = *(const bf16x8*)(vsc + fOff[ci][h]);
        }

#pragma unroll
      for (int rb = 0; rb < 2; ++rb) {
        // ---- S^T = K Q^T (swapped). C: row=quad*4+r -> kcol ci*16+quad*4+r,
        //                               col=c        -> q-row row0+rb*16+c
        f32x4 sc[4];
#pragma unroll
        for (int ci = 0; ci < 4; ++ci) {
          f32x4 acc = (f32x4){-FIXM, -FIXM, -FIXM, -FIXM};
          acc = __builtin_amdgcn_mfma_f32_16x16x32_bf16(kf[ci][0], qa[rb][0], acc, 0, 0, 0);
          acc = __builtin_amdgcn_mfma_f32_16x16x32_bf16(kf[ci][1], qa[rb][1], acc, 0, 0, 0);
          sc[ci] = acc;
        }
        if (kt == ktdiag) {   // diagonal tile mask
          const int grow = row0 + rb * 16 + c;
#pragma unroll
          for (int ci = 0; ci < 4; ++ci)
#pragma unroll
            for (int r = 0; r < 4; ++r)
              if (kt * 64 + ci * 16 + quad * 4 + r > grow) sc[ci][r] = -1e30f;
        }
        // ---- softmax (fixed max) + pack to bf16 words
        unsigned int Wt[4][2];
#pragma unroll
        for (int ci = 0; ci < 4; ++ci) {
#pragma unroll
          for (int r = 0; r < 4; ++r)
            sc[ci][r] = __builtin_amdgcn_exp2f(sc[ci][r]);
          ls[rb] += (sc[ci][0] + sc[ci][1]) + (sc[ci][2] + sc[ci][3]);
          Wt[ci][0] = cvtpk_bf16(sc[ci][0], sc[ci][1]);
          Wt[ci][1] = cvtpk_bf16(sc[ci][2], sc[ci][3]);
        }
        // ---- in-register P transpose (verified round 6):
        // word (srcQuad s, block b) -> quad 2(b&1)+(s>>1); 32-swap + 16-swap
        unsigned int a00 = Wt[0][0], a02 = Wt[1][0]; swap32(a00, a02); swap16(a00, a02);
        unsigned int a01 = Wt[0][1], a03 = Wt[1][1]; swap32(a01, a03); swap16(a01, a03);
        unsigned int a10 = Wt[2][0], a12 = Wt[3][0]; swap32(a10, a12); swap16(a10, a12);
        unsigned int a11 = Wt[2][1], a13 = Wt[3][1]; swap32(a11, a13); swap16(a11, a13);
        const bf16x8 pa0 = __builtin_bit_cast(bf16x8, (uint4v){a00, a01, a02, a03});
        const bf16x8 pa1 = __builtin_bit_cast(bf16x8, (uint4v){a10, a11, a12, a13});

        // ---- O += P V
#pragma unroll
        for (int ci = 0; ci < 4; ++ci) {
          oa[rb][ci] = __builtin_amdgcn_mfma_f32_16x16x32_bf16(pa0, vf[ci][0], oa[rb][ci], 0, 0, 0);
          oa[rb][ci] = __builtin_amdgcn_mfma_f32_16x16x32_bf16(pa1, vf[ci][1], oa[rb][ci], 0, 0, 0);
        }
      }
    }
  }

  // ---- epilogue: quad-reduce row sums, redistribute, O/l, fp32 stores
#pragma unroll
  for (int rb = 0; rb < 2; ++rb) {
    float tot = ls[rb];                 // lane (c,quad): partial for row row0+rb*16+c
    tot += __shfl_xor(tot, 16, 64);
    tot += __shfl_xor(tot, 32, 64);     // full sum in all 4 quad copies
    float inv[4];
#pragma unroll
    for (int r = 0; r < 4; ++r)
      inv[r] = 1.0f / __shfl(tot, quad * 4 + r, 64);  // row row0+rb*16+quad*4+r
#pragma unroll
    for (int ci = 0; ci < 4; ++ci)
#pragma unroll
      for (int r = 0; r < 4; ++r)
        Ob[(size_t)(row0 + rb * 16 + quad * 4 + r) * D_HEAD + ci * 16 + c] =
            oa[rb][ci][r] * inv[r];
  }
}

// ---------------- fallback (fp32 inputs direct) if ws too small
__global__ __launch_bounds__(256, 4)
void fa_fb(const float* __restrict__ Qg, const float* __restrict__ Kg,
           const float* __restrict__ Vg, float* __restrict__ Og)
{
  __shared__ __align__(16) unsigned short Ksh[64][72];
  __shared__ __align__(16) unsigned short Vsh[64][72];
  __shared__ __align__(16) unsigned short Psh[4][16][72];
  const int id = blockIdx.x;
  const int bh = id & 31;
  const int p  = id >> 5;
  const int t    = threadIdx.x;
  const int w    = t >> 6;
  const int lane = t & 63;
  const int c    = lane & 15;
  const int quad = lane >> 4;
  const size_t base = (size_t)bh * (S_LEN * D_HEAD);
  const float* __restrict__ Qb = Qg + base;
  const float* __restrict__ Kb = Kg + base;
  const float* __restrict__ Vb = Vg + base;
  float* __restrict__ Ob = Og + base;
  const int wv   = w & 1;
  const int row0 = (w >= 2) ? (S_LEN - 32 * (p + 1) + 16 * wv) : (32 * p + 16 * wv);
  const int ktdiag = row0 >> 6;
  const int ktmax  = (S_LEN - 1 - 32 * p) >> 6;
  bf16x8 qa[2];
  {
    const float* qp = Qb + (size_t)(row0 + c) * D_HEAD + quad * 8;
#pragma unroll
    for (int h = 0; h < 2; ++h) {
      f32x4 a0 = *(const f32x4*)(qp + 32 * h);
      f32x4 a1 = *(const f32x4*)(qp + 32 * h + 4);
#pragma unroll
      for (int j = 0; j < 4; ++j) {
        qa[h][j]     = (short)f2bf(a0[j] * SCALE_L2E);
        qa[h][4 + j] = (short)f2bf(a1[j] * SCALE_L2E);
      }
    }
  }
  f32x4 oa[4];
  float ls[4];
#pragma unroll
  for (int i = 0; i < 4; ++i) {
    oa[i] = (f32x4){0.f, 0.f, 0.f, 0.f};
    ls[i] = 0.f;
  }
  for (int kt = 0; kt <= ktmax; ++kt) {
    __syncthreads();
    {
      const int cp = t & 15;
      const int rg = t >> 4;
      const int col0 = cp * 4;
      const int sw = (cp >> 2) << 3;
#pragma unroll
      for (int i = 0; i < 4; ++i) {
        const int row = i * 16 + rg;
        const size_t goff = (size_t)(kt * 64 + row) * D_HEAD + col0;
        const f32x4 kv = *(const f32x4*)(Kb + goff);
        const f32x4 vv = *(const f32x4*)(Vb + goff);
        const unsigned int k01 = (rnd_bf(kv[1]) & 0xFFFF0000u) | (rnd_bf(kv[0]) >> 16);
        const unsigned int k23 = (rnd_bf(kv[3]) & 0xFFFF0000u) | (rnd_bf(kv[2]) >> 16);
        *(uint2*)&Ksh[row][col0] = make_uint2(k01, k23);
        const int kz = row ^ sw;
#pragma unroll
        for (int e = 0; e < 4; ++e)
          Vsh[col0 + e][kz] = f2bf(vv[e]);
      }
    }
    __syncthreads();
    if (kt <= ktdiag) {
      bf16x8 kf[4][2], vf[4][2];
#pragma unroll
      for (int ci = 0; ci < 4; ++ci) {
        kf[ci][0] = *(const bf16x8*)&Ksh[ci * 16 + c][quad * 8];
        kf[ci][1] = *(const bf16x8*)&Ksh[ci * 16 + c][32 + quad * 8];
        vf[ci][0] = *(const bf16x8*)&Vsh[ci * 16 + c][(quad ^ ci) * 8];
        vf[ci][1] = *(const bf16x8*)&Vsh[ci * 16 + c][32 + ((quad ^ ci) * 8)];
      }
      f32x4 sc[4];
#pragma unroll
      for (int ci = 0; ci < 4; ++ci) {
        f32x4 acc = (f32x4){-FIXM, -FIXM, -FIXM, -FIXM};
        acc = __builtin_amdgcn_mfma_f32_16x16x32_bf16(qa[0], kf[ci][0], acc, 0, 0, 0);
        acc = __builtin_amdgcn_mfma_f32_16x16x32_bf16(qa[1], kf[ci][1], acc, 0, 0, 0);
        sc[ci] = acc;
      }
      if (kt == ktdiag) {
#pragma unroll
        for (int ci = 0; ci < 4; ++ci) {
          const int gcol = kt * 64 + ci * 16 + c;
#pragma unroll
          for (int r = 0; r < 4; ++r)
            if (gcol > row0 + quad * 4 + r) sc[ci][r] = -1e30f;
        }
      }
#pragma unroll
      for (int ci = 0; ci < 4; ++ci)
#pragma unroll
        for (int r = 0; r < 4; ++r)
          sc[ci][r] = __builtin_amdgcn_exp2f(sc[ci][r]);
#pragma unroll
      for (int r = 0; r < 4; ++r)
        ls[r] += (sc[0][r] + sc[1][r]) + (sc[2][r] + sc[3][r]);
#pragma unroll
      for (int ci = 0; ci < 4; ++ci)
#pragma unroll
        for (int r = 0; r < 4; ++r) {
          const int prow = quad * 4 + r;
          Psh[w][prow][(ci * 16 + c) ^ ((prow >> 3) << 3)] = f2bf(sc[ci][r]);
        }
      const int px = (c >> 3) << 3;
      const bf16x8 pa0 = *(const bf16x8*)&Psh[w][c][(quad * 8) ^ px];
      const bf16x8 pa1 = *(const bf16x8*)&Psh[w][c][((32 + quad * 8)) ^ px];
#pragma unroll
      for (int ci = 0; ci < 4; ++ci) {
        oa[ci] = __builtin_amdgcn_mfma_f32_16x16x32_bf16(pa0, vf[ci][0], oa[ci], 0, 0, 0);
        oa[ci] = __builtin_amdgcn_mfma_f32_16x16x32_bf16(pa1, vf[ci][1], oa[ci], 0, 0, 0);
      }
    }
  }
  {
    float inv[4];
#pragma unroll
    for (int r = 0; r < 4; ++r) inv[r] = 1.0f / rowsum16(ls[r]);
#pragma unroll
    for (int ci = 0; ci < 4; ++ci)
#pragma unroll
      for (int r = 0; r < 4; ++r)
        Ob[(size_t)(row0 + quad * 4 + r) * D_HEAD + ci * 16 + c] = oa[ci][r] * inv[r];
  }
}

extern "C" void kernel_launch(void* const* d_in, const int* in_sizes, int n_in,
                              void* d_out, int out_size, void* d_ws, size_t ws_size,
                              hipStream_t stream) {
  (void)in_sizes; (void)n_in; (void)out_size;
  const float* Q = (const float*)d_in[0];
  const float* K = (const float*)d_in[1];
  const float* V = (const float*)d_in[2];
  float* O = (float*)d_out;   // d_in[3] (causal mask) computed analytically
  const size_t NEED = 2ull * 32 * S_LEN * D_HEAD * 2;  // Kb16 + Vt = 16 MB
  if (ws_size >= NEED) {
    unsigned short* Kb = (unsigned short*)d_ws;
    unsigned short* Vt = Kb + (size_t)32 * S_LEN * D_HEAD;
    prep<<<dim3(512), dim3(256), 0, stream>>>(K, V, Kb, Vt);
    fa<<<dim3(1024), dim3(128), 0, stream>>>(Q, Kb, Vt, O);
  } else {
    fa_fb<<<dim3(1024), dim3(256), 0, stream>>>(Q, K, V, O);
  }
}

// Round 3
// 137.016 us; speedup vs baseline: 1.2481x; 1.0306x over previous
//
#include <hip/hip_runtime.h>
#include <math.h>

// Causal MHA forward, B=2 H=16 S=2048 D=64, fp32 in/out, bf16 MFMA compute.
// Round 8: uniform-work blocks, zero idle waves.
//  - Block = 4 waves x 16 rows = one 64-row tile-row. Each block processes
//    tile-row i (kt=0..i) then tile-row 31-i (kt=0..31-i): exactly 33
//    barrier-iterations per block, every wave active every iteration
//    (all rows of a tile-row share diag kt). 512 blocks -> 2/CU, uniform.
//  - Keeps verified swapped-QK^T + in-register P transpose (cvt_pk+permlane),
//    gl_lds staging with xor swizzle, fixed-max softmax.
//  - s_setprio(1) around MFMA/softmax region (T5).

#define S_LEN   2048
#define D_HEAD  64
#define SCALE_L2E 0.18033688011112042f   // (1/sqrt(D)) * log2(e)
#define FIXM    8.0f                     // fixed softmax offset (exponent-safe)

using bf16x8 = __attribute__((ext_vector_type(8))) short;
using f32x4  = __attribute__((ext_vector_type(4))) float;
using uint4v = __attribute__((ext_vector_type(4))) unsigned int;

__device__ __forceinline__ unsigned int rnd_bf(float f) {
  return __float_as_uint(f) + 0x8000u;
}
__device__ __forceinline__ unsigned short f2bf(float f) {
  return (unsigned short)(rnd_bf(f) >> 16);
}

// async global->LDS, 16B per lane; LDS dest = uniform base + lane*16
__device__ __forceinline__ void gl_lds16(const unsigned short* g, unsigned short* l) {
  __builtin_amdgcn_global_load_lds(
      (const __attribute__((address_space(1))) unsigned int*)g,
      (__attribute__((address_space(3))) unsigned int*)l, 16, 0, 0);
}

// pack two f32 -> one dword of 2 x bf16 (lo = first arg)
__device__ __forceinline__ unsigned int cvtpk_bf16(float lo, float hi) {
  unsigned int r;
  asm("v_cvt_pk_bf16_f32 %0, %1, %2" : "=v"(r) : "v"(lo), "v"(hi));
  return r;
}
// a' = [a.lo32, b.lo32]; b' = [a.hi32, b.hi32]
__device__ __forceinline__ void swap32(unsigned int& a, unsigned int& b) {
  asm("v_permlane32_swap_b32 %0, %1" : "+v"(a), "+v"(b));
}
// rows = 16-lane groups: a' = [a.r0, b.r0, a.r2, b.r2]; b' = [a.r1, b.r1, a.r3, b.r3]
__device__ __forceinline__ void swap16(unsigned int& a, unsigned int& b) {
  asm("v_permlane16_swap_b32 %0, %1" : "+v"(a), "+v"(b));
}

// DPP cross-lane 16-wide sum (fa_fb epilogue only)
template <int CTRL>
__device__ __forceinline__ float dppf(float x) {
  return __builtin_bit_cast(float,
      __builtin_amdgcn_update_dpp(0, __builtin_bit_cast(int, x), CTRL, 0xF, 0xF, false));
}
__device__ __forceinline__ float rowsum16(float x) {
  x += dppf<0xB1>(x);
  x += dppf<0x4E>(x);
  x += dppf<0x124>(x);
  x += dppf<0x128>(x);
  return x;
}

// ---------------- pre-pass: K -> bf16 [bh][s][d]; V -> bf16 transposed [bh][d][s]
__global__ __launch_bounds__(256, 4)
void prep(const float* __restrict__ Kg, const float* __restrict__ Vg,
          unsigned short* __restrict__ Kb, unsigned short* __restrict__ Vt)
{
  __shared__ __align__(16) unsigned short Lt[64][72];
  const int j = blockIdx.x, t = threadIdx.x;
  const int bh = j >> 4, seg = j & 15;
  const size_t base = (size_t)bh * (S_LEN * D_HEAD) + (size_t)seg * 128 * D_HEAD;
#pragma unroll
  for (int i = 0; i < 8; ++i) {
    const size_t idx = base + i * 1024 + t * 4;
    const f32x4 v = *(const f32x4*)(Kg + idx);
    uint2 pk;
    pk.x = (rnd_bf(v[1]) & 0xFFFF0000u) | (rnd_bf(v[0]) >> 16);
    pk.y = (rnd_bf(v[3]) & 0xFFFF0000u) | (rnd_bf(v[2]) >> 16);
    *(uint2*)(Kb + idx) = pk;
  }
  for (int h = 0; h < 2; ++h) {
    const int s0 = seg * 128 + h * 64;
    __syncthreads();
#pragma unroll
    for (int pp = 0; pp < 4; ++pp) {
      const int r = t >> 2;
      const int d0 = (t & 3) * 4 + pp * 16;
      const f32x4 v = *(const f32x4*)(Vg + (size_t)bh * (S_LEN * D_HEAD)
                                         + (size_t)(s0 + r) * D_HEAD + d0);
#pragma unroll
      for (int e = 0; e < 4; ++e) Lt[d0 + e][r] = f2bf(v[e]);
    }
    __syncthreads();
#pragma unroll
    for (int q = 0; q < 2; ++q) {
      const int d = t >> 2, ch = (t & 3) + 4 * q;
      *(uint4*)(Vt + (size_t)(bh * 64 + d) * S_LEN + s0 + ch * 8) =
          *(const uint4*)&Lt[d][ch * 8];
    }
  }
}

// ---------------- main attention kernel: 4 waves x 16 rows, paired tile-rows
__global__ __launch_bounds__(256, 2)
void fa(const float* __restrict__ Qg, const unsigned short* __restrict__ Kb,
        const unsigned short* __restrict__ Vt, float* __restrict__ Og)
{
  __shared__ unsigned short Ks[2][64][64];   // 16 KB
  __shared__ unsigned short Vs[2][64][64];   // 16 KB -> 32 KB, 2 blk/CU (grid)

  const int id = blockIdx.x;            // 512 blocks
  const int bh = id & 31;               // id%8 == bh%8 -> head-local XCD L2 reuse
  const int pr = id >> 5;               // tile-row pair index 0..15

  const int t    = threadIdx.x;         // 0..255
  const int w    = t >> 6;
  const int lane = t & 63;
  const int c    = lane & 15;
  const int quad = lane >> 4;

  const float* __restrict__ Qb = Qg + (size_t)bh * (S_LEN * D_HEAD);
  float* __restrict__ Ob = Og + (size_t)bh * (S_LEN * D_HEAD);

  // ---- loop-invariant swizzled LDS offsets (shorts); same for K and V tiles
  int fOff[4][2];
#pragma unroll
  for (int ci = 0; ci < 4; ++ci)
#pragma unroll
    for (int h = 0; h < 2; ++h)
      fOff[ci][h] = ((ci * 16 + c) << 6) + (((h * 4 + quad) ^ (c & 7)) << 3);

  // per-wave staging: 2 instrs K + 2 instrs V, 16 rows each wave
  const int rl = lane >> 3;
  const int jj = (lane & 7) ^ rl;
  auto stage = [&](int kt, int buf) {
#pragma unroll
    for (int n = 0; n < 2; ++n) {
      const int row = w * 16 + n * 8 + rl;
      gl_lds16(Kb + (((size_t)(bh * S_LEN + kt * 64 + row)) << 6) + jj * 8,
               &Ks[buf][w * 16 + n * 8][0]);
      gl_lds16(Vt + (((size_t)(bh * 64 + row)) << 11) + kt * 64 + jj * 8,
               &Vs[buf][w * 16 + n * 8][0]);
    }
  };

  bf16x8 qa[2];
  f32x4 oa[4];
  float ls;

  int tog = 0;
  stage(0, 0);

#pragma unroll 1
  for (int ph = 0; ph < 2; ++ph) {
    const int tr   = ph ? (31 - pr) : pr;    // tile-row; diag kt == tr
    const int row0 = tr * 64 + w * 16;       // this wave's 16 rows

    // ---- Q fragment (B-operand of swapped QK^T), pre-scaled bf16
    {
      const float* qp = Qb + (size_t)(row0 + c) * D_HEAD + quad * 8;
#pragma unroll
      for (int h = 0; h < 2; ++h) {
        f32x4 a0 = *(const f32x4*)(qp + 32 * h);
        f32x4 a1 = *(const f32x4*)(qp + 32 * h + 4);
#pragma unroll
        for (int j = 0; j < 4; ++j) {
          qa[h][j]     = (short)f2bf(a0[j] * SCALE_L2E);
          qa[h][4 + j] = (short)f2bf(a1[j] * SCALE_L2E);
        }
      }
    }
#pragma unroll
    for (int i = 0; i < 4; ++i) oa[i] = (f32x4){0.f, 0.f, 0.f, 0.f};
    ls = 0.f;

#pragma unroll 1
    for (int kt = 0; kt <= tr; ++kt) {
      __syncthreads();                   // drains prefetch + prior LDS reads
      const int nxt = tog ^ 1;
      if (kt < tr)            stage(kt + 1, nxt);
      else if (ph == 0)       stage(0, nxt);   // handoff: phase-1 tile 0

      // ---- fragments from LDS
      const unsigned short* ksc = &Ks[tog][0][0];
      const unsigned short* vsc = &Vs[tog][0][0];
      bf16x8 kf[4][2], vf[4][2];
#pragma unroll
      for (int ci = 0; ci < 4; ++ci)
#pragma unroll
        for (int h = 0; h < 2; ++h) {
          kf[ci][h] = *(const bf16x8*)(ksc + fOff[ci][h]);
          vf[ci][h] = *(const bf16x8*)(vsc + fOff[ci][h]);
        }

      __builtin_amdgcn_s_setprio(1);
      // ---- S^T = K Q^T (swapped). C: row=quad*4+r -> kcol ci*16+quad*4+r,
      //                               col=c        -> q-row row0+c
      f32x4 sc[4];
#pragma unroll
      for (int ci = 0; ci < 4; ++ci) {
        f32x4 acc = (f32x4){-FIXM, -FIXM, -FIXM, -FIXM};
        acc = __builtin_amdgcn_mfma_f32_16x16x32_bf16(kf[ci][0], qa[0], acc, 0, 0, 0);
        acc = __builtin_amdgcn_mfma_f32_16x16x32_bf16(kf[ci][1], qa[1], acc, 0, 0, 0);
        sc[ci] = acc;
      }
      if (kt == tr) {   // diagonal tile mask (all waves mask at kt==tr)
        const int grow = row0 + c;
#pragma unroll
        for (int ci = 0; ci < 4; ++ci)
#pragma unroll
          for (int r = 0; r < 4; ++r)
            if (kt * 64 + ci * 16 + quad * 4 + r > grow) sc[ci][r] = -1e30f;
      }
      // ---- softmax (fixed max) + pack to bf16 words
      unsigned int Wt[4][2];
#pragma unroll
      for (int ci = 0; ci < 4; ++ci) {
#pragma unroll
        for (int r = 0; r < 4; ++r)
          sc[ci][r] = __builtin_amdgcn_exp2f(sc[ci][r]);
        ls += (sc[ci][0] + sc[ci][1]) + (sc[ci][2] + sc[ci][3]);
        Wt[ci][0] = cvtpk_bf16(sc[ci][0], sc[ci][1]);
        Wt[ci][1] = cvtpk_bf16(sc[ci][2], sc[ci][3]);
      }
      // ---- in-register P transpose (verified rounds 6-7):
      // word (srcQuad s, block b) -> quad 2(b&1)+(s>>1); 32-swap + 16-swap
      unsigned int a00 = Wt[0][0], a02 = Wt[1][0]; swap32(a00, a02); swap16(a00, a02);
      unsigned int a01 = Wt[0][1], a03 = Wt[1][1]; swap32(a01, a03); swap16(a01, a03);
      unsigned int a10 = Wt[2][0], a12 = Wt[3][0]; swap32(a10, a12); swap16(a10, a12);
      unsigned int a11 = Wt[2][1], a13 = Wt[3][1]; swap32(a11, a13); swap16(a11, a13);
      const bf16x8 pa0 = __builtin_bit_cast(bf16x8, (uint4v){a00, a01, a02, a03});
      const bf16x8 pa1 = __builtin_bit_cast(bf16x8, (uint4v){a10, a11, a12, a13});

      // ---- O += P V
#pragma unroll
      for (int ci = 0; ci < 4; ++ci) {
        oa[ci] = __builtin_amdgcn_mfma_f32_16x16x32_bf16(pa0, vf[ci][0], oa[ci], 0, 0, 0);
        oa[ci] = __builtin_amdgcn_mfma_f32_16x16x32_bf16(pa1, vf[ci][1], oa[ci], 0, 0, 0);
      }
      __builtin_amdgcn_s_setprio(0);

      tog = nxt;
    }

    // ---- epilogue: quad-reduce row sums, redistribute, O/l, fp32 stores
    {
      float tot = ls;                   // lane (c,quad): partial for row row0+c
      tot += __shfl_xor(tot, 16, 64);
      tot += __shfl_xor(tot, 32, 64);   // full sum in all 4 quad copies
      float inv[4];
#pragma unroll
      for (int r = 0; r < 4; ++r)
        inv[r] = 1.0f / __shfl(tot, quad * 4 + r, 64);  // row row0+quad*4+r
#pragma unroll
      for (int ci = 0; ci < 4; ++ci)
#pragma unroll
        for (int r = 0; r < 4; ++r)
          Ob[(size_t)(row0 + quad * 4 + r) * D_HEAD + ci * 16 + c] =
              oa[ci][r] * inv[r];
    }
  }
}

// ---------------- fallback (fp32 inputs direct) if ws too small
__global__ __launch_bounds__(256, 4)
void fa_fb(const float* __restrict__ Qg, const float* __restrict__ Kg,
           const float* __restrict__ Vg, float* __restrict__ Og)
{
  __shared__ __align__(16) unsigned short Ksh[64][72];
  __shared__ __align__(16) unsigned short Vsh[64][72];
  __shared__ __align__(16) unsigned short Psh[4][16][72];
  const int id = blockIdx.x;
  const int bh = id & 31;
  const int p  = id >> 5;
  const int t    = threadIdx.x;
  const int w    = t >> 6;
  const int lane = t & 63;
  const int c    = lane & 15;
  const int quad = lane >> 4;
  const size_t base = (size_t)bh * (S_LEN * D_HEAD);
  const float* __restrict__ Qb = Qg + base;
  const float* __restrict__ Kb = Kg + base;
  const float* __restrict__ Vb = Vg + base;
  float* __restrict__ Ob = Og + base;
  const int wv   = w & 1;
  const int row0 = (w >= 2) ? (S_LEN - 32 * (p + 1) + 16 * wv) : (32 * p + 16 * wv);
  const int ktdiag = row0 >> 6;
  const int ktmax  = (S_LEN - 1 - 32 * p) >> 6;
  bf16x8 qa[2];
  {
    const float* qp = Qb + (size_t)(row0 + c) * D_HEAD + quad * 8;
#pragma unroll
    for (int h = 0; h < 2; ++h) {
      f32x4 a0 = *(const f32x4*)(qp + 32 * h);
      f32x4 a1 = *(const f32x4*)(qp + 32 * h + 4);
#pragma unroll
      for (int j = 0; j < 4; ++j) {
        qa[h][j]     = (short)f2bf(a0[j] * SCALE_L2E);
        qa[h][4 + j] = (short)f2bf(a1[j] * SCALE_L2E);
      }
    }
  }
  f32x4 oa[4];
  float ls[4];
#pragma unroll
  for (int i = 0; i < 4; ++i) {
    oa[i] = (f32x4){0.f, 0.f, 0.f, 0.f};
    ls[i] = 0.f;
  }
  for (int kt = 0; kt <= ktmax; ++kt) {
    __syncthreads();
    {
      const int cp = t & 15;
      const int rg = t >> 4;
      const int col0 = cp * 4;
      const int sw = (cp >> 2) << 3;
#pragma unroll
      for (int i = 0; i < 4; ++i) {
        const int row = i * 16 + rg;
        const size_t goff = (size_t)(kt * 64 + row) * D_HEAD + col0;
        const f32x4 kv = *(const f32x4*)(Kb + goff);
        const f32x4 vv = *(const f32x4*)(Vb + goff);
        const unsigned int k01 = (rnd_bf(kv[1]) & 0xFFFF0000u) | (rnd_bf(kv[0]) >> 16);
        const unsigned int k23 = (rnd_bf(kv[3]) & 0xFFFF0000u) | (rnd_bf(kv[2]) >> 16);
        *(uint2*)&Ksh[row][col0] = make_uint2(k01, k23);
        const int kz = row ^ sw;
#pragma unroll
        for (int e = 0; e < 4; ++e)
          Vsh[col0 + e][kz] = f2bf(vv[e]);
      }
    }
    __syncthreads();
    if (kt <= ktdiag) {
      bf16x8 kf[4][2], vf[4][2];
#pragma unroll
      for (int ci = 0; ci < 4; ++ci) {
        kf[ci][0] = *(const bf16x8*)&Ksh[ci * 16 + c][quad * 8];
        kf[ci][1] = *(const bf16x8*)&Ksh[ci * 16 + c][32 + quad * 8];
        vf[ci][0] = *(const bf16x8*)&Vsh[ci * 16 + c][(quad ^ ci) * 8];
        vf[ci][1] = *(const bf16x8*)&Vsh[ci * 16 + c][32 + ((quad ^ ci) * 8)];
      }
      f32x4 sc[4];
#pragma unroll
      for (int ci = 0; ci < 4; ++ci) {
        f32x4 acc = (f32x4){-FIXM, -FIXM, -FIXM, -FIXM};
        acc = __builtin_amdgcn_mfma_f32_16x16x32_bf16(qa[0], kf[ci][0], acc, 0, 0, 0);
        acc = __builtin_amdgcn_mfma_f32_16x16x32_bf16(qa[1], kf[ci][1], acc, 0, 0, 0);
        sc[ci] = acc;
      }
      if (kt == ktdiag) {
#pragma unroll
        for (int ci = 0; ci < 4; ++ci) {
          const int gcol = kt * 64 + ci * 16 + c;
#pragma unroll
          for (int r = 0; r < 4; ++r)
            if (gcol > row0 + quad * 4 + r) sc[ci][r] = -1e30f;
        }
      }
#pragma unroll
      for (int ci = 0; ci < 4; ++ci)
#pragma unroll
        for (int r = 0; r < 4; ++r)
          sc[ci][r] = __builtin_amdgcn_exp2f(sc[ci][r]);
#pragma unroll
      for (int r = 0; r < 4; ++r)
        ls[r] += (sc[0][r] + sc[1][r]) + (sc[2][r] + sc[3][r]);
#pragma unroll
      for (int ci = 0; ci < 4; ++ci)
#pragma unroll
        for (int r = 0; r < 4; ++r) {
          const int prow = quad * 4 + r;
          Psh[w][prow][(ci * 16 + c) ^ ((prow >> 3) << 3)] = f2bf(sc[ci][r]);
        }
      const int px = (c >> 3) << 3;
      const bf16x8 pa0 = *(const bf16x8*)&Psh[w][c][(quad * 8) ^ px];
      const bf16x8 pa1 = *(const bf16x8*)&Psh[w][c][((32 + quad * 8)) ^ px];
#pragma unroll
      for (int ci = 0; ci < 4; ++ci) {
        oa[ci] = __builtin_amdgcn_mfma_f32_16x16x32_bf16(pa0, vf[ci][0], oa[ci], 0, 0, 0);
        oa[ci] = __builtin_amdgcn_mfma_f32_16x16x32_bf16(pa1, vf[ci][1], oa[ci], 0, 0, 0);
      }
    }
  }
  {
    float inv[4];
#pragma unroll
    for (int r = 0; r < 4; ++r) inv[r] = 1.0f / rowsum16(ls[r]);
#pragma unroll
    for (int ci = 0; ci < 4; ++ci)
#pragma unroll
      for (int r = 0; r < 4; ++r)
        Ob[(size_t)(row0 + quad * 4 + r) * D_HEAD + ci * 16 + c] = oa[ci][r] * inv[r];
  }
}

extern "C" void kernel_launch(void* const* d_in, const int* in_sizes, int n_in,
                              void* d_out, int out_size, void* d_ws, size_t ws_size,
                              hipStream_t stream) {
  (void)in_sizes; (void)n_in; (void)out_size;
  const float* Q = (const float*)d_in[0];
  const float* K = (const float*)d_in[1];
  const float* V = (const float*)d_in[2];
  float* O = (float*)d_out;   // d_in[3] (causal mask) computed analytically
  const size_t NEED = 2ull * 32 * S_LEN * D_HEAD * 2;  // Kb16 + Vt = 16 MB
  if (ws_size >= NEED) {
    unsigned short* Kb = (unsigned short*)d_ws;
    unsigned short* Vt = Kb + (size_t)32 * S_LEN * D_HEAD;
    prep<<<dim3(512), dim3(256), 0, stream>>>(K, V, Kb, Vt);
    fa<<<dim3(512), dim3(256), 0, stream>>>(Q, Kb, Vt, O);
  } else {
    fa_fb<<<dim3(1024), dim3(256), 0, stream>>>(Q, K, V, O);
  }
}

// Round 4
// 135.542 us; speedup vs baseline: 1.2616x; 1.0109x over previous
//
#include <hip/hip_runtime.h>
#include <math.h>

// Causal MHA forward, B=2 H=16 S=2048 D=64, fp32 in/out, bf16 MFMA compute.
// Round 9: split-K wave groups -> 2x resident waves (16/CU, 4/SIMD).
//  - Block = 8 waves (512 thr): group 0 (waves 0-3) = even kt, group 1 = odd kt,
//    same 64 q-rows (wave wg owns rows tr*64+wg*16). Fixed-max softmax makes the
//    merge a pure sum (same max): O = O0+O1, l = l0+l1, via LDS at phase end
//    (reuses just-freed staging buffer).
//  - Per-phase slots = ceil(n/2); ceil((32-pr)/2)+ceil((pr+1)/2) == 17 for all
//    blocks -> uniform, <=1 idle wave-slot. 512 blocks, 64 KB LDS -> 2 blk/CU.
//  - Keeps verified swapped-QK^T, in-register P transpose (cvt_pk+permlane),
//    gl_lds xor-swizzled staging, s_setprio.

#define S_LEN   2048
#define D_HEAD  64
#define SCALE_L2E 0.18033688011112042f   // (1/sqrt(D)) * log2(e)
#define FIXM    8.0f                     // fixed softmax offset (exponent-safe)

using bf16x8 = __attribute__((ext_vector_type(8))) short;
using f32x4  = __attribute__((ext_vector_type(4))) float;
using uint4v = __attribute__((ext_vector_type(4))) unsigned int;

__device__ __forceinline__ unsigned int rnd_bf(float f) {
  return __float_as_uint(f) + 0x8000u;
}
__device__ __forceinline__ unsigned short f2bf(float f) {
  return (unsigned short)(rnd_bf(f) >> 16);
}

// async global->LDS, 16B per lane; LDS dest = uniform base + lane*16
__device__ __forceinline__ void gl_lds16(const unsigned short* g, unsigned short* l) {
  __builtin_amdgcn_global_load_lds(
      (const __attribute__((address_space(1))) unsigned int*)g,
      (__attribute__((address_space(3))) unsigned int*)l, 16, 0, 0);
}

// pack two f32 -> one dword of 2 x bf16 (lo = first arg)
__device__ __forceinline__ unsigned int cvtpk_bf16(float lo, float hi) {
  unsigned int r;
  asm("v_cvt_pk_bf16_f32 %0, %1, %2" : "=v"(r) : "v"(lo), "v"(hi));
  return r;
}
// a' = [a.lo32, b.lo32]; b' = [a.hi32, b.hi32]
__device__ __forceinline__ void swap32(unsigned int& a, unsigned int& b) {
  asm("v_permlane32_swap_b32 %0, %1" : "+v"(a), "+v"(b));
}
// rows = 16-lane groups: a' = [a.r0, b.r0, a.r2, b.r2]; b' = [a.r1, b.r1, a.r3, b.r3]
__device__ __forceinline__ void swap16(unsigned int& a, unsigned int& b) {
  asm("v_permlane16_swap_b32 %0, %1" : "+v"(a), "+v"(b));
}

// DPP cross-lane 16-wide sum (fa_fb epilogue only)
template <int CTRL>
__device__ __forceinline__ float dppf(float x) {
  return __builtin_bit_cast(float,
      __builtin_amdgcn_update_dpp(0, __builtin_bit_cast(int, x), CTRL, 0xF, 0xF, false));
}
__device__ __forceinline__ float rowsum16(float x) {
  x += dppf<0xB1>(x);
  x += dppf<0x4E>(x);
  x += dppf<0x124>(x);
  x += dppf<0x128>(x);
  return x;
}

// ---------------- pre-pass: K -> bf16 [bh][s][d]; V -> bf16 transposed [bh][d][s]
__global__ __launch_bounds__(256, 4)
void prep(const float* __restrict__ Kg, const float* __restrict__ Vg,
          unsigned short* __restrict__ Kb, unsigned short* __restrict__ Vt)
{
  __shared__ __align__(16) unsigned short Lt[64][72];
  const int j = blockIdx.x, t = threadIdx.x;
  const int bh = j >> 4, seg = j & 15;
  const size_t base = (size_t)bh * (S_LEN * D_HEAD) + (size_t)seg * 128 * D_HEAD;
#pragma unroll
  for (int i = 0; i < 8; ++i) {
    const size_t idx = base + i * 1024 + t * 4;
    const f32x4 v = *(const f32x4*)(Kg + idx);
    uint2 pk;
    pk.x = (rnd_bf(v[1]) & 0xFFFF0000u) | (rnd_bf(v[0]) >> 16);
    pk.y = (rnd_bf(v[3]) & 0xFFFF0000u) | (rnd_bf(v[2]) >> 16);
    *(uint2*)(Kb + idx) = pk;
  }
  for (int h = 0; h < 2; ++h) {
    const int s0 = seg * 128 + h * 64;
    __syncthreads();
#pragma unroll
    for (int pp = 0; pp < 4; ++pp) {
      const int r = t >> 2;
      const int d0 = (t & 3) * 4 + pp * 16;
      const f32x4 v = *(const f32x4*)(Vg + (size_t)bh * (S_LEN * D_HEAD)
                                         + (size_t)(s0 + r) * D_HEAD + d0);
#pragma unroll
      for (int e = 0; e < 4; ++e) Lt[d0 + e][r] = f2bf(v[e]);
    }
    __syncthreads();
#pragma unroll
    for (int q = 0; q < 2; ++q) {
      const int d = t >> 2, ch = (t & 3) + 4 * q;
      *(uint4*)(Vt + (size_t)(bh * 64 + d) * S_LEN + s0 + ch * 8) =
          *(const uint4*)&Lt[d][ch * 8];
    }
  }
}

// ---------------- main attention: 8 waves = 2 k-parity groups x 4 row-waves
__global__ __launch_bounds__(512, 4)
void fa(const float* __restrict__ Qg, const unsigned short* __restrict__ Kb,
        const unsigned short* __restrict__ Vt, float* __restrict__ Og)
{
  __shared__ unsigned short Ks[2][2][64][64];   // [group][buf] 32 KB
  __shared__ unsigned short Vs[2][2][64][64];   // 32 KB -> 64 KB, 2 blk/CU

  const int id = blockIdx.x;            // 512 blocks
  const int bh = id & 31;               // id%8 == bh%8 -> head-local XCD L2 reuse
  const int pr = id >> 5;               // tile-row pair 0..15

  const int t    = threadIdx.x;         // 0..511
  const int w8   = t >> 6;              // 0..7
  const int g    = w8 >> 2;             // k-parity group: kt ≡ g (mod 2)
  const int wg   = w8 & 3;              // row-wave within group
  const int lane = t & 63;
  const int c    = lane & 15;
  const int quad = lane >> 4;

  const float* __restrict__ Qb = Qg + (size_t)bh * (S_LEN * D_HEAD);
  float* __restrict__ Ob = Og + (size_t)bh * (S_LEN * D_HEAD);

  // ---- loop-invariant swizzled LDS offsets (shorts); same for K and V tiles
  int fOff[4][2];
#pragma unroll
  for (int ci = 0; ci < 4; ++ci)
#pragma unroll
    for (int h = 0; h < 2; ++h)
      fOff[ci][h] = ((ci * 16 + c) << 6) + (((h * 4 + quad) ^ (c & 7)) << 3);

  // per-wave staging: 2 instrs K + 2 instrs V, 16 rows each wave (group's tile)
  const int rl = lane >> 3;
  const int jj = (lane & 7) ^ rl;
  auto stage = [&](int kt, int buf) {
#pragma unroll
    for (int n = 0; n < 2; ++n) {
      const int row = wg * 16 + n * 8 + rl;
      gl_lds16(Kb + (((size_t)(bh * S_LEN + kt * 64 + row)) << 6) + jj * 8,
               &Ks[g][buf][wg * 16 + n * 8][0]);
      gl_lds16(Vt + (((size_t)(bh * 64 + row)) << 11) + kt * 64 + jj * 8,
               &Vs[g][buf][wg * 16 + n * 8][0]);
    }
  };

  bf16x8 qa[2];
  f32x4 oa[4];
  float ls;

  int slot = 0;
  stage(g, 0);   // prologue: group g's first tile (kt=g <= 16 <= trA always)

#pragma unroll 1
  for (int ph = 0; ph < 2; ++ph) {
    const int tr   = ph ? pr : (31 - pr);    // tile-row; diag at kt == tr
    const int row0 = tr * 64 + wg * 16;      // this wave's 16 rows
    const int hs   = (tr + 2) >> 1;          // slots this phase = ceil((tr+1)/2)

    // ---- Q fragment (B-operand of swapped QK^T), pre-scaled bf16
    {
      const float* qp = Qb + (size_t)(row0 + c) * D_HEAD + quad * 8;
#pragma unroll
      for (int h = 0; h < 2; ++h) {
        f32x4 a0 = *(const f32x4*)(qp + 32 * h);
        f32x4 a1 = *(const f32x4*)(qp + 32 * h + 4);
#pragma unroll
        for (int j = 0; j < 4; ++j) {
          qa[h][j]     = (short)f2bf(a0[j] * SCALE_L2E);
          qa[h][4 + j] = (short)f2bf(a1[j] * SCALE_L2E);
        }
      }
    }
#pragma unroll
    for (int i = 0; i < 4; ++i) oa[i] = (f32x4){0.f, 0.f, 0.f, 0.f};
    ls = 0.f;

#pragma unroll 1
    for (int it = 0; it < hs; ++it, ++slot) {
      const int kt  = 2 * it + g;
      const int tog = slot & 1;
      __syncthreads();                   // drains prefetch + prior LDS reads
      // stage my group's next tile (kt+2), or hand off to next phase's first
      const int ktn = kt + 2;
      if (ktn <= tr)
        stage(ktn, tog ^ 1);
      else if (ph == 0 && it == hs - 1 && g <= pr)
        stage(g, tog ^ 1);               // phase-B first tile (kt = g)

      if (kt <= tr) {
        // ---- fragments from this group's LDS buffer
        const unsigned short* ksc = &Ks[g][tog][0][0];
        const unsigned short* vsc = &Vs[g][tog][0][0];
        bf16x8 kf[4][2], vf[4][2];
#pragma unroll
        for (int ci = 0; ci < 4; ++ci)
#pragma unroll
          for (int h = 0; h < 2; ++h) {
            kf[ci][h] = *(const bf16x8*)(ksc + fOff[ci][h]);
            vf[ci][h] = *(const bf16x8*)(vsc + fOff[ci][h]);
          }

        __builtin_amdgcn_s_setprio(1);
        // ---- S^T = K Q^T (swapped). C: row=quad*4+r -> kcol ci*16+quad*4+r,
        //                               col=c        -> q-row row0+c
        f32x4 sc[4];
#pragma unroll
        for (int ci = 0; ci < 4; ++ci) {
          f32x4 acc = (f32x4){-FIXM, -FIXM, -FIXM, -FIXM};
          acc = __builtin_amdgcn_mfma_f32_16x16x32_bf16(kf[ci][0], qa[0], acc, 0, 0, 0);
          acc = __builtin_amdgcn_mfma_f32_16x16x32_bf16(kf[ci][1], qa[1], acc, 0, 0, 0);
          sc[ci] = acc;
        }
        if (kt == tr) {   // diagonal tile mask
          const int grow = row0 + c;
#pragma unroll
          for (int ci = 0; ci < 4; ++ci)
#pragma unroll
            for (int r = 0; r < 4; ++r)
              if (kt * 64 + ci * 16 + quad * 4 + r > grow) sc[ci][r] = -1e30f;
        }
        // ---- softmax (fixed max) + pack to bf16 words
        unsigned int Wt[4][2];
#pragma unroll
        for (int ci = 0; ci < 4; ++ci) {
#pragma unroll
          for (int r = 0; r < 4; ++r)
            sc[ci][r] = __builtin_amdgcn_exp2f(sc[ci][r]);
          ls += (sc[ci][0] + sc[ci][1]) + (sc[ci][2] + sc[ci][3]);
          Wt[ci][0] = cvtpk_bf16(sc[ci][0], sc[ci][1]);
          Wt[ci][1] = cvtpk_bf16(sc[ci][2], sc[ci][3]);
        }
        // ---- in-register P transpose (verified rounds 6-8):
        // word (srcQuad s, block b) -> quad 2(b&1)+(s>>1); 32-swap + 16-swap
        unsigned int a00 = Wt[0][0], a02 = Wt[1][0]; swap32(a00, a02); swap16(a00, a02);
        unsigned int a01 = Wt[0][1], a03 = Wt[1][1]; swap32(a01, a03); swap16(a01, a03);
        unsigned int a10 = Wt[2][0], a12 = Wt[3][0]; swap32(a10, a12); swap16(a10, a12);
        unsigned int a11 = Wt[2][1], a13 = Wt[3][1]; swap32(a11, a13); swap16(a11, a13);
        const bf16x8 pa0 = __builtin_bit_cast(bf16x8, (uint4v){a00, a01, a02, a03});
        const bf16x8 pa1 = __builtin_bit_cast(bf16x8, (uint4v){a10, a11, a12, a13});

        // ---- O += P V
#pragma unroll
        for (int ci = 0; ci < 4; ++ci) {
          oa[ci] = __builtin_amdgcn_mfma_f32_16x16x32_bf16(pa0, vf[ci][0], oa[ci], 0, 0, 0);
          oa[ci] = __builtin_amdgcn_mfma_f32_16x16x32_bf16(pa1, vf[ci][1], oa[ci], 0, 0, 0);
        }
        __builtin_amdgcn_s_setprio(0);
      }
    }

    // ---- phase-end merge: group 1 -> LDS (freed staging buf), group 0 stores
    // free parity: last slot consumed (slot-1)&1; prefetched next-phase tile
    // sits in slot&1 -> disjoint.
    const int fp = (slot & 1) ^ 1;
    __syncthreads();
    if (g == 1) {
      float* exo = (float*)&Vs[wg >> 1][fp][0][0] + (wg & 1) * 1024;
#pragma unroll
      for (int ci = 0; ci < 4; ++ci)
#pragma unroll
        for (int r = 0; r < 4; ++r)
          exo[(ci * 4 + r) * 64 + lane] = oa[ci][r];   // lane-contiguous, no conflicts
      ((float*)&Ks[0][fp][0][0])[wg * 64 + lane] = ls;
    }
    __syncthreads();
    if (g == 0) {
      const float* exo = (const float*)&Vs[wg >> 1][fp][0][0] + (wg & 1) * 1024;
      float tot = ls + ((const float*)&Ks[0][fp][0][0])[wg * 64 + lane];
      tot += __shfl_xor(tot, 16, 64);
      tot += __shfl_xor(tot, 32, 64);   // full row sum in all 4 quad copies
      float inv[4];
#pragma unroll
      for (int r = 0; r < 4; ++r)
        inv[r] = 1.0f / __shfl(tot, quad * 4 + r, 64);  // row row0+quad*4+r
#pragma unroll
      for (int ci = 0; ci < 4; ++ci)
#pragma unroll
        for (int r = 0; r < 4; ++r) {
          const float ov = oa[ci][r] + exo[(ci * 4 + r) * 64 + lane];
          Ob[(size_t)(row0 + quad * 4 + r) * D_HEAD + ci * 16 + c] = ov * inv[r];
        }
    }
  }
}

// ---------------- fallback (fp32 inputs direct) if ws too small
__global__ __launch_bounds__(256, 4)
void fa_fb(const float* __restrict__ Qg, const float* __restrict__ Kg,
           const float* __restrict__ Vg, float* __restrict__ Og)
{
  __shared__ __align__(16) unsigned short Ksh[64][72];
  __shared__ __align__(16) unsigned short Vsh[64][72];
  __shared__ __align__(16) unsigned short Psh[4][16][72];
  const int id = blockIdx.x;
  const int bh = id & 31;
  const int p  = id >> 5;
  const int t    = threadIdx.x;
  const int w    = t >> 6;
  const int lane = t & 63;
  const int c    = lane & 15;
  const int quad = lane >> 4;
  const size_t base = (size_t)bh * (S_LEN * D_HEAD);
  const float* __restrict__ Qb = Qg + base;
  const float* __restrict__ Kb = Kg + base;
  const float* __restrict__ Vb = Vg + base;
  float* __restrict__ Ob = Og + base;
  const int wv   = w & 1;
  const int row0 = (w >= 2) ? (S_LEN - 32 * (p + 1) + 16 * wv) : (32 * p + 16 * wv);
  const int ktdiag = row0 >> 6;
  const int ktmax  = (S_LEN - 1 - 32 * p) >> 6;
  bf16x8 qa[2];
  {
    const float* qp = Qb + (size_t)(row0 + c) * D_HEAD + quad * 8;
#pragma unroll
    for (int h = 0; h < 2; ++h) {
      f32x4 a0 = *(const f32x4*)(qp + 32 * h);
      f32x4 a1 = *(const f32x4*)(qp + 32 * h + 4);
#pragma unroll
      for (int j = 0; j < 4; ++j) {
        qa[h][j]     = (short)f2bf(a0[j] * SCALE_L2E);
        qa[h][4 + j] = (short)f2bf(a1[j] * SCALE_L2E);
      }
    }
  }
  f32x4 oa[4];
  float ls[4];
#pragma unroll
  for (int i = 0; i < 4; ++i) {
    oa[i] = (f32x4){0.f, 0.f, 0.f, 0.f};
    ls[i] = 0.f;
  }
  for (int kt = 0; kt <= ktmax; ++kt) {
    __syncthreads();
    {
      const int cp = t & 15;
      const int rg = t >> 4;
      const int col0 = cp * 4;
      const int sw = (cp >> 2) << 3;
#pragma unroll
      for (int i = 0; i < 4; ++i) {
        const int row = i * 16 + rg;
        const size_t goff = (size_t)(kt * 64 + row) * D_HEAD + col0;
        const f32x4 kv = *(const f32x4*)(Kb + goff);
        const f32x4 vv = *(const f32x4*)(Vb + goff);
        const unsigned int k01 = (rnd_bf(kv[1]) & 0xFFFF0000u) | (rnd_bf(kv[0]) >> 16);
        const unsigned int k23 = (rnd_bf(kv[3]) & 0xFFFF0000u) | (rnd_bf(kv[2]) >> 16);
        *(uint2*)&Ksh[row][col0] = make_uint2(k01, k23);
        const int kz = row ^ sw;
#pragma unroll
        for (int e = 0; e < 4; ++e)
          Vsh[col0 + e][kz] = f2bf(vv[e]);
      }
    }
    __syncthreads();
    if (kt <= ktdiag) {
      bf16x8 kf[4][2], vf[4][2];
#pragma unroll
      for (int ci = 0; ci < 4; ++ci) {
        kf[ci][0] = *(const bf16x8*)&Ksh[ci * 16 + c][quad * 8];
        kf[ci][1] = *(const bf16x8*)&Ksh[ci * 16 + c][32 + quad * 8];
        vf[ci][0] = *(const bf16x8*)&Vsh[ci * 16 + c][(quad ^ ci) * 8];
        vf[ci][1] = *(const bf16x8*)&Vsh[ci * 16 + c][32 + ((quad ^ ci) * 8)];
      }
      f32x4 sc[4];
#pragma unroll
      for (int ci = 0; ci < 4; ++ci) {
        f32x4 acc = (f32x4){-FIXM, -FIXM, -FIXM, -FIXM};
        acc = __builtin_amdgcn_mfma_f32_16x16x32_bf16(qa[0], kf[ci][0], acc, 0, 0, 0);
        acc = __builtin_amdgcn_mfma_f32_16x16x32_bf16(qa[1], kf[ci][1], acc, 0, 0, 0);
        sc[ci] = acc;
      }
      if (kt == ktdiag) {
#pragma unroll
        for (int ci = 0; ci < 4; ++ci) {
          const int gcol = kt * 64 + ci * 16 + c;
#pragma unroll
          for (int r = 0; r < 4; ++r)
            if (gcol > row0 + quad * 4 + r) sc[ci][r] = -1e30f;
        }
      }
#pragma unroll
      for (int ci = 0; ci < 4; ++ci)
#pragma unroll
        for (int r = 0; r < 4; ++r)
          sc[ci][r] = __builtin_amdgcn_exp2f(sc[ci][r]);
#pragma unroll
      for (int r = 0; r < 4; ++r)
        ls[r] += (sc[0][r] + sc[1][r]) + (sc[2][r] + sc[3][r]);
#pragma unroll
      for (int ci = 0; ci < 4; ++ci)
#pragma unroll
        for (int r = 0; r < 4; ++r) {
          const int prow = quad * 4 + r;
          Psh[w][prow][(ci * 16 + c) ^ ((prow >> 3) << 3)] = f2bf(sc[ci][r]);
        }
      const int px = (c >> 3) << 3;
      const bf16x8 pa0 = *(const bf16x8*)&Psh[w][c][(quad * 8) ^ px];
      const bf16x8 pa1 = *(const bf16x8*)&Psh[w][c][((32 + quad * 8)) ^ px];
#pragma unroll
      for (int ci = 0; ci < 4; ++ci) {
        oa[ci] = __builtin_amdgcn_mfma_f32_16x16x32_bf16(pa0, vf[ci][0], oa[ci], 0, 0, 0);
        oa[ci] = __builtin_amdgcn_mfma_f32_16x16x32_bf16(pa1, vf[ci][1], oa[ci], 0, 0, 0);
      }
    }
  }
  {
    float inv[4];
#pragma unroll
    for (int r = 0; r < 4; ++r) inv[r] = 1.0f / rowsum16(ls[r]);
#pragma unroll
    for (int ci = 0; ci < 4; ++ci)
#pragma unroll
      for (int r = 0; r < 4; ++r)
        Ob[(size_t)(row0 + quad * 4 + r) * D_HEAD + ci * 16 + c] = oa[ci][r] * inv[r];
  }
}

extern "C" void kernel_launch(void* const* d_in, const int* in_sizes, int n_in,
                              void* d_out, int out_size, void* d_ws, size_t ws_size,
                              hipStream_t stream) {
  (void)in_sizes; (void)n_in; (void)out_size;
  const float* Q = (const float*)d_in[0];
  const float* K = (const float*)d_in[1];
  const float* V = (const float*)d_in[2];
  float* O = (float*)d_out;   // d_in[3] (causal mask) computed analytically
  const size_t NEED = 2ull * 32 * S_LEN * D_HEAD * 2;  // Kb16 + Vt = 16 MB
  if (ws_size >= NEED) {
    unsigned short* Kb = (unsigned short*)d_ws;
    unsigned short* Vt = Kb + (size_t)32 * S_LEN * D_HEAD;
    prep<<<dim3(512), dim3(256), 0, stream>>>(K, V, Kb, Vt);
    fa<<<dim3(512), dim3(512), 0, stream>>>(Q, Kb, Vt, O);
  } else {
    fa_fb<<<dim3(1024), dim3(256), 0, stream>>>(Q, K, V, O);
  }
}

// Round 5
// 131.543 us; speedup vs baseline: 1.3000x; 1.0304x over previous
//
#include <hip/hip_runtime.h>
#include <math.h>

// Causal MHA forward, B=2 H=16 S=2048 D=64, fp32 in/out, bf16 MFMA compute.
// Round 10: revert round-9 split-K (regressed: per-iteration wall scales with
// waves/SIMD -> barrier-serialization, not latency-capacity). Base = round 8
// (uniform paired tile-rows, 41.8 us) + 128-col iterations: two 64-col
// sub-tiles per barrier interval. Iterations/block 33 -> 17 (uniform for all
// pr); sub-tile B's ds_read/QK-MFMA overlaps sub-tile A's softmax VALU within
// one interval; staging drain amortized over 2x work. LDS 64 KB, 2 blk/CU.
// Keeps verified swapped-QK^T, in-register P transpose (cvt_pk+permlane),
// gl_lds xor-swizzled staging, fixed-max softmax, s_setprio.

#define S_LEN   2048
#define D_HEAD  64
#define SCALE_L2E 0.18033688011112042f   // (1/sqrt(D)) * log2(e)
#define FIXM    8.0f                     // fixed softmax offset (exponent-safe)

using bf16x8 = __attribute__((ext_vector_type(8))) short;
using f32x4  = __attribute__((ext_vector_type(4))) float;
using uint4v = __attribute__((ext_vector_type(4))) unsigned int;

__device__ __forceinline__ unsigned int rnd_bf(float f) {
  return __float_as_uint(f) + 0x8000u;
}
__device__ __forceinline__ unsigned short f2bf(float f) {
  return (unsigned short)(rnd_bf(f) >> 16);
}

// async global->LDS, 16B per lane; LDS dest = uniform base + lane*16
__device__ __forceinline__ void gl_lds16(const unsigned short* g, unsigned short* l) {
  __builtin_amdgcn_global_load_lds(
      (const __attribute__((address_space(1))) unsigned int*)g,
      (__attribute__((address_space(3))) unsigned int*)l, 16, 0, 0);
}

// pack two f32 -> one dword of 2 x bf16 (lo = first arg)
__device__ __forceinline__ unsigned int cvtpk_bf16(float lo, float hi) {
  unsigned int r;
  asm("v_cvt_pk_bf16_f32 %0, %1, %2" : "=v"(r) : "v"(lo), "v"(hi));
  return r;
}
// a' = [a.lo32, b.lo32]; b' = [a.hi32, b.hi32]
__device__ __forceinline__ void swap32(unsigned int& a, unsigned int& b) {
  asm("v_permlane32_swap_b32 %0, %1" : "+v"(a), "+v"(b));
}
// rows = 16-lane groups: a' = [a.r0, b.r0, a.r2, b.r2]; b' = [a.r1, b.r1, a.r3, b.r3]
__device__ __forceinline__ void swap16(unsigned int& a, unsigned int& b) {
  asm("v_permlane16_swap_b32 %0, %1" : "+v"(a), "+v"(b));
}

// DPP cross-lane 16-wide sum (fa_fb epilogue only)
template <int CTRL>
__device__ __forceinline__ float dppf(float x) {
  return __builtin_bit_cast(float,
      __builtin_amdgcn_update_dpp(0, __builtin_bit_cast(int, x), CTRL, 0xF, 0xF, false));
}
__device__ __forceinline__ float rowsum16(float x) {
  x += dppf<0xB1>(x);
  x += dppf<0x4E>(x);
  x += dppf<0x124>(x);
  x += dppf<0x128>(x);
  return x;
}

// ---------------- pre-pass: K -> bf16 [bh][s][d]; V -> bf16 transposed [bh][d][s]
__global__ __launch_bounds__(256, 4)
void prep(const float* __restrict__ Kg, const float* __restrict__ Vg,
          unsigned short* __restrict__ Kb, unsigned short* __restrict__ Vt)
{
  __shared__ __align__(16) unsigned short Lt[64][72];
  const int j = blockIdx.x, t = threadIdx.x;
  const int bh = j >> 4, seg = j & 15;
  const size_t base = (size_t)bh * (S_LEN * D_HEAD) + (size_t)seg * 128 * D_HEAD;
#pragma unroll
  for (int i = 0; i < 8; ++i) {
    const size_t idx = base + i * 1024 + t * 4;
    const f32x4 v = *(const f32x4*)(Kg + idx);
    uint2 pk;
    pk.x = (rnd_bf(v[1]) & 0xFFFF0000u) | (rnd_bf(v[0]) >> 16);
    pk.y = (rnd_bf(v[3]) & 0xFFFF0000u) | (rnd_bf(v[2]) >> 16);
    *(uint2*)(Kb + idx) = pk;
  }
  for (int h = 0; h < 2; ++h) {
    const int s0 = seg * 128 + h * 64;
    __syncthreads();
#pragma unroll
    for (int pp = 0; pp < 4; ++pp) {
      const int r = t >> 2;
      const int d0 = (t & 3) * 4 + pp * 16;
      const f32x4 v = *(const f32x4*)(Vg + (size_t)bh * (S_LEN * D_HEAD)
                                         + (size_t)(s0 + r) * D_HEAD + d0);
#pragma unroll
      for (int e = 0; e < 4; ++e) Lt[d0 + e][r] = f2bf(v[e]);
    }
    __syncthreads();
#pragma unroll
    for (int q = 0; q < 2; ++q) {
      const int d = t >> 2, ch = (t & 3) + 4 * q;
      *(uint4*)(Vt + (size_t)(bh * 64 + d) * S_LEN + s0 + ch * 8) =
          *(const uint4*)&Lt[d][ch * 8];
    }
  }
}

// ---------------- main attention: 4 waves x 16 rows, paired tile-rows,
// ---------------- two 64-col sub-tiles per barrier interval
__global__ __launch_bounds__(256, 2)
void fa(const float* __restrict__ Qg, const unsigned short* __restrict__ Kb,
        const unsigned short* __restrict__ Vt, float* __restrict__ Og)
{
  __shared__ unsigned short Ks[2][2][64][64];   // [buf][sub] 32 KB
  __shared__ unsigned short Vs[2][2][64][64];   // 32 KB -> 64 KB, 2 blk/CU

  const int id = blockIdx.x;            // 512 blocks
  const int bh = id & 31;               // id%8 == bh%8 -> head-local XCD L2 reuse
  const int pr = id >> 5;               // tile-row pair 0..15

  const int t    = threadIdx.x;         // 0..255
  const int w    = t >> 6;
  const int lane = t & 63;
  const int c    = lane & 15;
  const int quad = lane >> 4;

  const float* __restrict__ Qb = Qg + (size_t)bh * (S_LEN * D_HEAD);
  float* __restrict__ Ob = Og + (size_t)bh * (S_LEN * D_HEAD);

  const int tr0 = pr, tr1 = 31 - pr;

  // ---- loop-invariant swizzled LDS offsets (shorts); same for K and V tiles
  int fOff[4][2];
#pragma unroll
  for (int ci = 0; ci < 4; ++ci)
#pragma unroll
    for (int h = 0; h < 2; ++h)
      fOff[ci][h] = ((ci * 16 + c) << 6) + (((h * 4 + quad) ^ (c & 7)) << 3);

  // per-wave staging: 2 instrs K + 2 instrs V per 64-col sub-tile
  const int rl = lane >> 3;
  const int jj = (lane & 7) ^ rl;
  auto stage1 = [&](int kt, int buf, int sub) {
#pragma unroll
    for (int n = 0; n < 2; ++n) {
      const int row = w * 16 + n * 8 + rl;
      gl_lds16(Kb + (((size_t)(bh * S_LEN + kt * 64 + row)) << 6) + jj * 8,
               &Ks[buf][sub][w * 16 + n * 8][0]);
      gl_lds16(Vt + (((size_t)(bh * 64 + row)) << 11) + kt * 64 + jj * 8,
               &Vs[buf][sub][w * 16 + n * 8][0]);
    }
  };
  auto stage_pair = [&](int it, int tr, int buf) {
    const int k0 = 2 * it;
    stage1(k0, buf, 0);                  // caller guarantees k0 <= tr
    if (k0 + 1 <= tr) stage1(k0 + 1, buf, 1);
  };

  bf16x8 qa[2];
  f32x4 oa[4];
  float ls;

  int buf = 0;
  stage_pair(0, tr0, 0);                 // prologue: phase-0 pair 0

#pragma unroll 1
  for (int ph = 0; ph < 2; ++ph) {
    const int tr    = ph ? tr1 : tr0;    // tile-row; diag at kt == tr
    const int row0  = tr * 64 + w * 16;  // this wave's 16 rows
    const int iters = (tr + 2) >> 1;     // ceil((tr+1)/2); sums to 17 over phases

    // ---- Q fragment (B-operand of swapped QK^T), pre-scaled bf16
    {
      const float* qp = Qb + (size_t)(row0 + c) * D_HEAD + quad * 8;
#pragma unroll
      for (int h = 0; h < 2; ++h) {
        f32x4 a0 = *(const f32x4*)(qp + 32 * h);
        f32x4 a1 = *(const f32x4*)(qp + 32 * h + 4);
#pragma unroll
        for (int j = 0; j < 4; ++j) {
          qa[h][j]     = (short)f2bf(a0[j] * SCALE_L2E);
          qa[h][4 + j] = (short)f2bf(a1[j] * SCALE_L2E);
        }
      }
    }
#pragma unroll
    for (int i = 0; i < 4; ++i) oa[i] = (f32x4){0.f, 0.f, 0.f, 0.f};
    ls = 0.f;

#pragma unroll 1
    for (int it = 0; it < iters; ++it) {
      __syncthreads();                   // drains prefetch + prior LDS reads
      // prefetch next pair (or hand off to phase 1's first pair)
      if (it + 1 < iters)  stage_pair(it + 1, tr, buf ^ 1);
      else if (ph == 0)    stage_pair(0, tr1, buf ^ 1);

#pragma unroll
      for (int s = 0; s < 2; ++s) {
        const int kt = 2 * it + s;
        if (kt <= tr) {
          // ---- fragments from LDS
          const unsigned short* ksc = &Ks[buf][s][0][0];
          const unsigned short* vsc = &Vs[buf][s][0][0];
          bf16x8 kf[4][2], vf[4][2];
#pragma unroll
          for (int ci = 0; ci < 4; ++ci)
#pragma unroll
            for (int h = 0; h < 2; ++h) {
              kf[ci][h] = *(const bf16x8*)(ksc + fOff[ci][h]);
              vf[ci][h] = *(const bf16x8*)(vsc + fOff[ci][h]);
            }

          __builtin_amdgcn_s_setprio(1);
          // ---- S^T = K Q^T (swapped). C: row=quad*4+r -> kcol ci*16+quad*4+r,
          //                               col=c        -> q-row row0+c
          f32x4 sc[4];
#pragma unroll
          for (int ci = 0; ci < 4; ++ci) {
            f32x4 acc = (f32x4){-FIXM, -FIXM, -FIXM, -FIXM};
            acc = __builtin_amdgcn_mfma_f32_16x16x32_bf16(kf[ci][0], qa[0], acc, 0, 0, 0);
            acc = __builtin_amdgcn_mfma_f32_16x16x32_bf16(kf[ci][1], qa[1], acc, 0, 0, 0);
            sc[ci] = acc;
          }
          if (kt == tr) {   // diagonal tile mask
            const int grow = row0 + c;
#pragma unroll
            for (int ci = 0; ci < 4; ++ci)
#pragma unroll
              for (int r = 0; r < 4; ++r)
                if (kt * 64 + ci * 16 + quad * 4 + r > grow) sc[ci][r] = -1e30f;
          }
          // ---- softmax (fixed max) + pack to bf16 words
          unsigned int Wt[4][2];
#pragma unroll
          for (int ci = 0; ci < 4; ++ci) {
#pragma unroll
            for (int r = 0; r < 4; ++r)
              sc[ci][r] = __builtin_amdgcn_exp2f(sc[ci][r]);
            ls += (sc[ci][0] + sc[ci][1]) + (sc[ci][2] + sc[ci][3]);
            Wt[ci][0] = cvtpk_bf16(sc[ci][0], sc[ci][1]);
            Wt[ci][1] = cvtpk_bf16(sc[ci][2], sc[ci][3]);
          }
          // ---- in-register P transpose (verified rounds 6-9):
          // word (srcQuad sq, block b) -> quad 2(b&1)+(sq>>1); 32-swap + 16-swap
          unsigned int a00 = Wt[0][0], a02 = Wt[1][0]; swap32(a00, a02); swap16(a00, a02);
          unsigned int a01 = Wt[0][1], a03 = Wt[1][1]; swap32(a01, a03); swap16(a01, a03);
          unsigned int a10 = Wt[2][0], a12 = Wt[3][0]; swap32(a10, a12); swap16(a10, a12);
          unsigned int a11 = Wt[2][1], a13 = Wt[3][1]; swap32(a11, a13); swap16(a11, a13);
          const bf16x8 pa0 = __builtin_bit_cast(bf16x8, (uint4v){a00, a01, a02, a03});
          const bf16x8 pa1 = __builtin_bit_cast(bf16x8, (uint4v){a10, a11, a12, a13});

          // ---- O += P V
#pragma unroll
          for (int ci = 0; ci < 4; ++ci) {
            oa[ci] = __builtin_amdgcn_mfma_f32_16x16x32_bf16(pa0, vf[ci][0], oa[ci], 0, 0, 0);
            oa[ci] = __builtin_amdgcn_mfma_f32_16x16x32_bf16(pa1, vf[ci][1], oa[ci], 0, 0, 0);
          }
          __builtin_amdgcn_s_setprio(0);
        }
      }
      buf ^= 1;
    }

    // ---- epilogue: quad-reduce row sums, redistribute, O/l, fp32 stores
    {
      float tot = ls;                   // lane (c,quad): partial for row row0+c
      tot += __shfl_xor(tot, 16, 64);
      tot += __shfl_xor(tot, 32, 64);   // full sum in all 4 quad copies
      float inv[4];
#pragma unroll
      for (int r = 0; r < 4; ++r)
        inv[r] = 1.0f / __shfl(tot, quad * 4 + r, 64);  // row row0+quad*4+r
#pragma unroll
      for (int ci = 0; ci < 4; ++ci)
#pragma unroll
        for (int r = 0; r < 4; ++r)
          Ob[(size_t)(row0 + quad * 4 + r) * D_HEAD + ci * 16 + c] =
              oa[ci][r] * inv[r];
    }
  }
}

// ---------------- fallback (fp32 inputs direct) if ws too small
__global__ __launch_bounds__(256, 4)
void fa_fb(const float* __restrict__ Qg, const float* __restrict__ Kg,
           const float* __restrict__ Vg, float* __restrict__ Og)
{
  __shared__ __align__(16) unsigned short Ksh[64][72];
  __shared__ __align__(16) unsigned short Vsh[64][72];
  __shared__ __align__(16) unsigned short Psh[4][16][72];
  const int id = blockIdx.x;
  const int bh = id & 31;
  const int p  = id >> 5;
  const int t    = threadIdx.x;
  const int w    = t >> 6;
  const int lane = t & 63;
  const int c    = lane & 15;
  const int quad = lane >> 4;
  const size_t base = (size_t)bh * (S_LEN * D_HEAD);
  const float* __restrict__ Qb = Qg + base;
  const float* __restrict__ Kb = Kg + base;
  const float* __restrict__ Vb = Vg + base;
  float* __restrict__ Ob = Og + base;
  const int wv   = w & 1;
  const int row0 = (w >= 2) ? (S_LEN - 32 * (p + 1) + 16 * wv) : (32 * p + 16 * wv);
  const int ktdiag = row0 >> 6;
  const int ktmax  = (S_LEN - 1 - 32 * p) >> 6;
  bf16x8 qa[2];
  {
    const float* qp = Qb + (size_t)(row0 + c) * D_HEAD + quad * 8;
#pragma unroll
    for (int h = 0; h < 2; ++h) {
      f32x4 a0 = *(const f32x4*)(qp + 32 * h);
      f32x4 a1 = *(const f32x4*)(qp + 32 * h + 4);
#pragma unroll
      for (int j = 0; j < 4; ++j) {
        qa[h][j]     = (short)f2bf(a0[j] * SCALE_L2E);
        qa[h][4 + j] = (short)f2bf(a1[j] * SCALE_L2E);
      }
    }
  }
  f32x4 oa[4];
  float ls[4];
#pragma unroll
  for (int i = 0; i < 4; ++i) {
    oa[i] = (f32x4){0.f, 0.f, 0.f, 0.f};
    ls[i] = 0.f;
  }
  for (int kt = 0; kt <= ktmax; ++kt) {
    __syncthreads();
    {
      const int cp = t & 15;
      const int rg = t >> 4;
      const int col0 = cp * 4;
      const int sw = (cp >> 2) << 3;
#pragma unroll
      for (int i = 0; i < 4; ++i) {
        const int row = i * 16 + rg;
        const size_t goff = (size_t)(kt * 64 + row) * D_HEAD + col0;
        const f32x4 kv = *(const f32x4*)(Kb + goff);
        const f32x4 vv = *(const f32x4*)(Vb + goff);
        const unsigned int k01 = (rnd_bf(kv[1]) & 0xFFFF0000u) | (rnd_bf(kv[0]) >> 16);
        const unsigned int k23 = (rnd_bf(kv[3]) & 0xFFFF0000u) | (rnd_bf(kv[2]) >> 16);
        *(uint2*)&Ksh[row][col0] = make_uint2(k01, k23);
        const int kz = row ^ sw;
#pragma unroll
        for (int e = 0; e < 4; ++e)
          Vsh[col0 + e][kz] = f2bf(vv[e]);
      }
    }
    __syncthreads();
    if (kt <= ktdiag) {
      bf16x8 kf[4][2], vf[4][2];
#pragma unroll
      for (int ci = 0; ci < 4; ++ci) {
        kf[ci][0] = *(const bf16x8*)&Ksh[ci * 16 + c][quad * 8];
        kf[ci][1] = *(const bf16x8*)&Ksh[ci * 16 + c][32 + quad * 8];
        vf[ci][0] = *(const bf16x8*)&Vsh[ci * 16 + c][(quad ^ ci) * 8];
        vf[ci][1] = *(const bf16x8*)&Vsh[ci * 16 + c][32 + ((quad ^ ci) * 8)];
      }
      f32x4 sc[4];
#pragma unroll
      for (int ci = 0; ci < 4; ++ci) {
        f32x4 acc = (f32x4){-FIXM, -FIXM, -FIXM, -FIXM};
        acc = __builtin_amdgcn_mfma_f32_16x16x32_bf16(qa[0], kf[ci][0], acc, 0, 0, 0);
        acc = __builtin_amdgcn_mfma_f32_16x16x32_bf16(qa[1], kf[ci][1], acc, 0, 0, 0);
        sc[ci] = acc;
      }
      if (kt == ktdiag) {
#pragma unroll
        for (int ci = 0; ci < 4; ++ci) {
          const int gcol = kt * 64 + ci * 16 + c;
#pragma unroll
          for (int r = 0; r < 4; ++r)
            if (gcol > row0 + quad * 4 + r) sc[ci][r] = -1e30f;
        }
      }
#pragma unroll
      for (int ci = 0; ci < 4; ++ci)
#pragma unroll
        for (int r = 0; r < 4; ++r)
          sc[ci][r] = __builtin_amdgcn_exp2f(sc[ci][r]);
#pragma unroll
      for (int r = 0; r < 4; ++r)
        ls[r] += (sc[0][r] + sc[1][r]) + (sc[2][r] + sc[3][r]);
#pragma unroll
      for (int ci = 0; ci < 4; ++ci)
#pragma unroll
        for (int r = 0; r < 4; ++r) {
          const int prow = quad * 4 + r;
          Psh[w][prow][(ci * 16 + c) ^ ((prow >> 3) << 3)] = f2bf(sc[ci][r]);
        }
      const int px = (c >> 3) << 3;
      const bf16x8 pa0 = *(const bf16x8*)&Psh[w][c][(quad * 8) ^ px];
      const bf16x8 pa1 = *(const bf16x8*)&Psh[w][c][((32 + quad * 8)) ^ px];
#pragma unroll
      for (int ci = 0; ci < 4; ++ci) {
        oa[ci] = __builtin_amdgcn_mfma_f32_16x16x32_bf16(pa0, vf[ci][0], oa[ci], 0, 0, 0);
        oa[ci] = __builtin_amdgcn_mfma_f32_16x16x32_bf16(pa1, vf[ci][1], oa[ci], 0, 0, 0);
      }
    }
  }
  {
    float inv[4];
#pragma unroll
    for (int r = 0; r < 4; ++r) inv[r] = 1.0f / rowsum16(ls[r]);
#pragma unroll
    for (int ci = 0; ci < 4; ++ci)
#pragma unroll
      for (int r = 0; r < 4; ++r)
        Ob[(size_t)(row0 + quad * 4 + r) * D_HEAD + ci * 16 + c] = oa[ci][r] * inv[r];
  }
}

extern "C" void kernel_launch(void* const* d_in, const int* in_sizes, int n_in,
                              void* d_out, int out_size, void* d_ws, size_t ws_size,
                              hipStream_t stream) {
  (void)in_sizes; (void)n_in; (void)out_size;
  const float* Q = (const float*)d_in[0];
  const float* K = (const float*)d_in[1];
  const float* V = (const float*)d_in[2];
  float* O = (float*)d_out;   // d_in[3] (causal mask) computed analytically
  const size_t NEED = 2ull * 32 * S_LEN * D_HEAD * 2;  // Kb16 + Vt = 16 MB
  if (ws_size >= NEED) {
    unsigned short* Kb = (unsigned short*)d_ws;
    unsigned short* Vt = Kb + (size_t)32 * S_LEN * D_HEAD;
    prep<<<dim3(512), dim3(256), 0, stream>>>(K, V, Kb, Vt);
    fa<<<dim3(512), dim3(256), 0, stream>>>(Q, Kb, Vt, O);
  } else {
    fa_fb<<<dim3(1024), dim3(256), 0, stream>>>(Q, K, V, O);
  }
}

// Round 7
// 130.776 us; speedup vs baseline: 1.3076x; 1.0059x over previous
//
#include <hip/hip_runtime.h>
#include <math.h>

// Causal MHA forward, B=2 H=16 S=2048 D=64, fp32 in/out, bf16 MFMA compute.
// Round 12 == round 11 resubmitted (bench infra failed; no counters). Changes
// vs round 10 base (fa ~36 us):
//  - Dovetailed sub-tiles: QK(s0), QK(s1), softmax(s0), softmax(s1), PV(s0),
//    PV(s1); vf ds_reads issued right after QK so their latency hides under
//    softmax VALU, and s1's MFMA overlaps s0's exp/pack on the other pipe.
//  - Row-sum l computed by MFMA against a ones B-fragment (lacc C-tile):
//    kills 32 serial VALU adds/interval AND the epilogue's 7 cross-lane
//    shuffles (lacc layout == oa layout; inv = 1/lacc directly).
//  - Keeps: paired tile-rows (uniform 17 intervals), 128-col intervals,
//    double-buffered gl_lds staging w/ xor swizzle, swapped QK^T,
//    in-register P transpose (cvt_pk + permlane), fixed-max softmax.

#define S_LEN   2048
#define D_HEAD  64
#define SCALE_L2E 0.18033688011112042f   // (1/sqrt(D)) * log2(e)
#define FIXM    8.0f                     // fixed softmax offset (exponent-safe)

using bf16x8 = __attribute__((ext_vector_type(8))) short;
using f32x4  = __attribute__((ext_vector_type(4))) float;
using uint4v = __attribute__((ext_vector_type(4))) unsigned int;

__device__ __forceinline__ unsigned int rnd_bf(float f) {
  return __float_as_uint(f) + 0x8000u;
}
__device__ __forceinline__ unsigned short f2bf(float f) {
  return (unsigned short)(rnd_bf(f) >> 16);
}

// async global->LDS, 16B per lane; LDS dest = uniform base + lane*16
__device__ __forceinline__ void gl_lds16(const unsigned short* g, unsigned short* l) {
  __builtin_amdgcn_global_load_lds(
      (const __attribute__((address_space(1))) unsigned int*)g,
      (__attribute__((address_space(3))) unsigned int*)l, 16, 0, 0);
}

// pack two f32 -> one dword of 2 x bf16 (lo = first arg)
__device__ __forceinline__ unsigned int cvtpk_bf16(float lo, float hi) {
  unsigned int r;
  asm("v_cvt_pk_bf16_f32 %0, %1, %2" : "=v"(r) : "v"(lo), "v"(hi));
  return r;
}
// a' = [a.lo32, b.lo32]; b' = [a.hi32, b.hi32]
__device__ __forceinline__ void swap32(unsigned int& a, unsigned int& b) {
  asm("v_permlane32_swap_b32 %0, %1" : "+v"(a), "+v"(b));
}
// rows = 16-lane groups: a' = [a.r0, b.r0, a.r2, b.r2]; b' = [a.r1, b.r1, a.r3, b.r3]
__device__ __forceinline__ void swap16(unsigned int& a, unsigned int& b) {
  asm("v_permlane16_swap_b32 %0, %1" : "+v"(a), "+v"(b));
}

// DPP cross-lane 16-wide sum (fa_fb epilogue only)
template <int CTRL>
__device__ __forceinline__ float dppf(float x) {
  return __builtin_bit_cast(float,
      __builtin_amdgcn_update_dpp(0, __builtin_bit_cast(int, x), CTRL, 0xF, 0xF, false));
}
__device__ __forceinline__ float rowsum16(float x) {
  x += dppf<0xB1>(x);
  x += dppf<0x4E>(x);
  x += dppf<0x124>(x);
  x += dppf<0x128>(x);
  return x;
}

// ---------------- pre-pass: K -> bf16 [bh][s][d]; V -> bf16 transposed [bh][d][s]
__global__ __launch_bounds__(256, 4)
void prep(const float* __restrict__ Kg, const float* __restrict__ Vg,
          unsigned short* __restrict__ Kb, unsigned short* __restrict__ Vt)
{
  __shared__ __align__(16) unsigned short Lt[64][72];
  const int j = blockIdx.x, t = threadIdx.x;
  const int bh = j >> 4, seg = j & 15;
  const size_t base = (size_t)bh * (S_LEN * D_HEAD) + (size_t)seg * 128 * D_HEAD;
#pragma unroll
  for (int i = 0; i < 8; ++i) {
    const size_t idx = base + i * 1024 + t * 4;
    const f32x4 v = *(const f32x4*)(Kg + idx);
    uint2 pk;
    pk.x = (rnd_bf(v[1]) & 0xFFFF0000u) | (rnd_bf(v[0]) >> 16);
    pk.y = (rnd_bf(v[3]) & 0xFFFF0000u) | (rnd_bf(v[2]) >> 16);
    *(uint2*)(Kb + idx) = pk;
  }
  for (int h = 0; h < 2; ++h) {
    const int s0 = seg * 128 + h * 64;
    __syncthreads();
#pragma unroll
    for (int pp = 0; pp < 4; ++pp) {
      const int r = t >> 2;
      const int d0 = (t & 3) * 4 + pp * 16;
      const f32x4 v = *(const f32x4*)(Vg + (size_t)bh * (S_LEN * D_HEAD)
                                         + (size_t)(s0 + r) * D_HEAD + d0);
#pragma unroll
      for (int e = 0; e < 4; ++e) Lt[d0 + e][r] = f2bf(v[e]);
    }
    __syncthreads();
#pragma unroll
    for (int q = 0; q < 2; ++q) {
      const int d = t >> 2, ch = (t & 3) + 4 * q;
      *(uint4*)(Vt + (size_t)(bh * 64 + d) * S_LEN + s0 + ch * 8) =
          *(const uint4*)&Lt[d][ch * 8];
    }
  }
}

// ---------------- main attention: 4 waves x 16 rows, paired tile-rows,
// ---------------- two dovetailed 64-col sub-tiles per barrier interval
__global__ __launch_bounds__(256, 2)
void fa(const float* __restrict__ Qg, const unsigned short* __restrict__ Kb,
        const unsigned short* __restrict__ Vt, float* __restrict__ Og)
{
  __shared__ unsigned short Ks[2][2][64][64];   // [buf][sub] 32 KB
  __shared__ unsigned short Vs[2][2][64][64];   // 32 KB -> 64 KB, 2 blk/CU

  const int id = blockIdx.x;            // 512 blocks
  const int bh = id & 31;               // id%8 == bh%8 -> head-local XCD L2 reuse
  const int pr = id >> 5;               // tile-row pair 0..15

  const int t    = threadIdx.x;         // 0..255
  const int w    = t >> 6;
  const int lane = t & 63;
  const int c    = lane & 15;
  const int quad = lane >> 4;

  const float* __restrict__ Qb = Qg + (size_t)bh * (S_LEN * D_HEAD);
  float* __restrict__ Ob = Og + (size_t)bh * (S_LEN * D_HEAD);

  const int tr0 = pr, tr1 = 31 - pr;

  // ---- loop-invariant swizzled LDS offsets (shorts); same for K and V tiles
  int fOff[4][2];
#pragma unroll
  for (int ci = 0; ci < 4; ++ci)
#pragma unroll
    for (int h = 0; h < 2; ++h)
      fOff[ci][h] = ((ci * 16 + c) << 6) + (((h * 4 + quad) ^ (c & 7)) << 3);

  // ones B-fragment for the row-sum MFMA (bf16 1.0)
  bf16x8 ones;
#pragma unroll
  for (int j = 0; j < 8; ++j) ones[j] = (short)0x3F80;

  // per-wave staging: 2 instrs K + 2 instrs V per 64-col sub-tile
  const int rl = lane >> 3;
  const int jj = (lane & 7) ^ rl;
  auto stage1 = [&](int kt, int buf, int sub) {
#pragma unroll
    for (int n = 0; n < 2; ++n) {
      const int row = w * 16 + n * 8 + rl;
      gl_lds16(Kb + (((size_t)(bh * S_LEN + kt * 64 + row)) << 6) + jj * 8,
               &Ks[buf][sub][w * 16 + n * 8][0]);
      gl_lds16(Vt + (((size_t)(bh * 64 + row)) << 11) + kt * 64 + jj * 8,
               &Vs[buf][sub][w * 16 + n * 8][0]);
    }
  };
  auto stage_pair = [&](int it, int tr, int buf) {
    const int k0 = 2 * it;
    stage1(k0, buf, 0);                  // caller guarantees k0 <= tr
    if (k0 + 1 <= tr) stage1(k0 + 1, buf, 1);
  };

  // softmax + pack + in-register transpose: sc (C layout) -> paX0/paX1 (A frags)
  auto smpack = [&](f32x4* sc, bf16x8& p0, bf16x8& p1) {
    unsigned int Wt[4][2];
#pragma unroll
    for (int ci = 0; ci < 4; ++ci) {
#pragma unroll
      for (int r = 0; r < 4; ++r)
        sc[ci][r] = __builtin_amdgcn_exp2f(sc[ci][r]);
      Wt[ci][0] = cvtpk_bf16(sc[ci][0], sc[ci][1]);
      Wt[ci][1] = cvtpk_bf16(sc[ci][2], sc[ci][3]);
    }
    // word (srcQuad sq, block b) -> quad 2(b&1)+(sq>>1); 32-swap + 16-swap
    unsigned int a00 = Wt[0][0], a02 = Wt[1][0]; swap32(a00, a02); swap16(a00, a02);
    unsigned int a01 = Wt[0][1], a03 = Wt[1][1]; swap32(a01, a03); swap16(a01, a03);
    unsigned int a10 = Wt[2][0], a12 = Wt[3][0]; swap32(a10, a12); swap16(a10, a12);
    unsigned int a11 = Wt[2][1], a13 = Wt[3][1]; swap32(a11, a13); swap16(a11, a13);
    p0 = __builtin_bit_cast(bf16x8, (uint4v){a00, a01, a02, a03});
    p1 = __builtin_bit_cast(bf16x8, (uint4v){a10, a11, a12, a13});
  };

  bf16x8 qa[2];
  f32x4 oa[4];
  f32x4 lacc;

  int buf = 0;
  stage_pair(0, tr0, 0);                 // prologue: phase-0 pair 0

#pragma unroll 1
  for (int ph = 0; ph < 2; ++ph) {
    const int tr    = ph ? tr1 : tr0;    // tile-row; diag at kt == tr
    const int row0  = tr * 64 + w * 16;  // this wave's 16 rows
    const int iters = (tr + 2) >> 1;     // ceil((tr+1)/2); sums to 17 over phases

    // ---- Q fragment (B-operand of swapped QK^T), pre-scaled bf16
    {
      const float* qp = Qb + (size_t)(row0 + c) * D_HEAD + quad * 8;
#pragma unroll
      for (int h = 0; h < 2; ++h) {
        f32x4 a0 = *(const f32x4*)(qp + 32 * h);
        f32x4 a1 = *(const f32x4*)(qp + 32 * h + 4);
#pragma unroll
        for (int j = 0; j < 4; ++j) {
          qa[h][j]     = (short)f2bf(a0[j] * SCALE_L2E);
          qa[h][4 + j] = (short)f2bf(a1[j] * SCALE_L2E);
        }
      }
    }
#pragma unroll
    for (int i = 0; i < 4; ++i) oa[i] = (f32x4){0.f, 0.f, 0.f, 0.f};
    lacc = (f32x4){0.f, 0.f, 0.f, 0.f};

#pragma unroll 1
    for (int it = 0; it < iters; ++it) {
      __syncthreads();                   // drains prefetch + prior LDS reads
      // prefetch next pair (or hand off to phase 1's first pair)
      if (it + 1 < iters)  stage_pair(it + 1, tr, buf ^ 1);
      else if (ph == 0)    stage_pair(0, tr1, buf ^ 1);

      const int kt0 = 2 * it, kt1 = kt0 + 1;
      const bool has1 = (kt1 <= tr);     // block-uniform

      // ---- K fragments (both sub-tiles)
      const unsigned short* ks0 = &Ks[buf][0][0][0];
      const unsigned short* ks1 = &Ks[buf][1][0][0];
      bf16x8 kf0[4][2], kf1[4][2];
#pragma unroll
      for (int ci = 0; ci < 4; ++ci)
#pragma unroll
        for (int h = 0; h < 2; ++h)
          kf0[ci][h] = *(const bf16x8*)(ks0 + fOff[ci][h]);
      if (has1)
#pragma unroll
        for (int ci = 0; ci < 4; ++ci)
#pragma unroll
          for (int h = 0; h < 2; ++h)
            kf1[ci][h] = *(const bf16x8*)(ks1 + fOff[ci][h]);

      __builtin_amdgcn_s_setprio(1);
      // ---- QK^T (swapped) for both sub-tiles
      f32x4 sc0[4], sc1[4];
#pragma unroll
      for (int ci = 0; ci < 4; ++ci) {
        f32x4 acc = (f32x4){-FIXM, -FIXM, -FIXM, -FIXM};
        acc = __builtin_amdgcn_mfma_f32_16x16x32_bf16(kf0[ci][0], qa[0], acc, 0, 0, 0);
        acc = __builtin_amdgcn_mfma_f32_16x16x32_bf16(kf0[ci][1], qa[1], acc, 0, 0, 0);
        sc0[ci] = acc;
      }
      if (has1)
#pragma unroll
        for (int ci = 0; ci < 4; ++ci) {
          f32x4 acc = (f32x4){-FIXM, -FIXM, -FIXM, -FIXM};
          acc = __builtin_amdgcn_mfma_f32_16x16x32_bf16(kf1[ci][0], qa[0], acc, 0, 0, 0);
          acc = __builtin_amdgcn_mfma_f32_16x16x32_bf16(kf1[ci][1], qa[1], acc, 0, 0, 0);
          sc1[ci] = acc;
        }

      // ---- V fragments issued now; latency hides under softmax VALU
      const unsigned short* vs0 = &Vs[buf][0][0][0];
      const unsigned short* vs1 = &Vs[buf][1][0][0];
      bf16x8 vf0[4][2], vf1[4][2];
#pragma unroll
      for (int ci = 0; ci < 4; ++ci)
#pragma unroll
        for (int h = 0; h < 2; ++h)
          vf0[ci][h] = *(const bf16x8*)(vs0 + fOff[ci][h]);
      if (has1)
#pragma unroll
        for (int ci = 0; ci < 4; ++ci)
#pragma unroll
          for (int h = 0; h < 2; ++h)
            vf1[ci][h] = *(const bf16x8*)(vs1 + fOff[ci][h]);

      // ---- diagonal masks (block-uniform predicates)
      if (kt0 == tr) {
        const int grow = row0 + c;
#pragma unroll
        for (int ci = 0; ci < 4; ++ci)
#pragma unroll
          for (int r = 0; r < 4; ++r)
            if (kt0 * 64 + ci * 16 + quad * 4 + r > grow) sc0[ci][r] = -1e30f;
      }
      if (has1 && kt1 == tr) {
        const int grow = row0 + c;
#pragma unroll
        for (int ci = 0; ci < 4; ++ci)
#pragma unroll
          for (int r = 0; r < 4; ++r)
            if (kt1 * 64 + ci * 16 + quad * 4 + r > grow) sc1[ci][r] = -1e30f;
      }

      // ---- softmax + pack + transpose (s0 then s1; overlaps QK/PV MFMA)
      bf16x8 paA0, paA1, paB0, paB1;
      smpack(sc0, paA0, paA1);
      if (has1) smpack(sc1, paB0, paB1);

      // ---- PV + row-sum MFMA (lacc layout == oa layout)
#pragma unroll
      for (int ci = 0; ci < 4; ++ci) {
        oa[ci] = __builtin_amdgcn_mfma_f32_16x16x32_bf16(paA0, vf0[ci][0], oa[ci], 0, 0, 0);
        oa[ci] = __builtin_amdgcn_mfma_f32_16x16x32_bf16(paA1, vf0[ci][1], oa[ci], 0, 0, 0);
      }
      lacc = __builtin_amdgcn_mfma_f32_16x16x32_bf16(paA0, ones, lacc, 0, 0, 0);
      lacc = __builtin_amdgcn_mfma_f32_16x16x32_bf16(paA1, ones, lacc, 0, 0, 0);
      if (has1) {
#pragma unroll
        for (int ci = 0; ci < 4; ++ci) {
          oa[ci] = __builtin_amdgcn_mfma_f32_16x16x32_bf16(paB0, vf1[ci][0], oa[ci], 0, 0, 0);
          oa[ci] = __builtin_amdgcn_mfma_f32_16x16x32_bf16(paB1, vf1[ci][1], oa[ci], 0, 0, 0);
        }
        lacc = __builtin_amdgcn_mfma_f32_16x16x32_bf16(paB0, ones, lacc, 0, 0, 0);
        lacc = __builtin_amdgcn_mfma_f32_16x16x32_bf16(paB1, ones, lacc, 0, 0, 0);
      }
      __builtin_amdgcn_s_setprio(0);

      buf ^= 1;
    }

    // ---- epilogue: no cross-lane work needed; lacc[r] = rowsum(q-row quad*4+r)
    {
      float inv[4];
#pragma unroll
      for (int r = 0; r < 4; ++r) inv[r] = 1.0f / lacc[r];
#pragma unroll
      for (int ci = 0; ci < 4; ++ci)
#pragma unroll
        for (int r = 0; r < 4; ++r)
          Ob[(size_t)(row0 + quad * 4 + r) * D_HEAD + ci * 16 + c] =
              oa[ci][r] * inv[r];
    }
  }
}

// ---------------- fallback (fp32 inputs direct) if ws too small
__global__ __launch_bounds__(256, 4)
void fa_fb(const float* __restrict__ Qg, const float* __restrict__ Kg,
           const float* __restrict__ Vg, float* __restrict__ Og)
{
  __shared__ __align__(16) unsigned short Ksh[64][72];
  __shared__ __align__(16) unsigned short Vsh[64][72];
  __shared__ __align__(16) unsigned short Psh[4][16][72];
  const int id = blockIdx.x;
  const int bh = id & 31;
  const int p  = id >> 5;
  const int t    = threadIdx.x;
  const int w    = t >> 6;
  const int lane = t & 63;
  const int c    = lane & 15;
  const int quad = lane >> 4;
  const size_t base = (size_t)bh * (S_LEN * D_HEAD);
  const float* __restrict__ Qb = Qg + base;
  const float* __restrict__ Kb = Kg + base;
  const float* __restrict__ Vb = Vg + base;
  float* __restrict__ Ob = Og + base;
  const int wv   = w & 1;
  const int row0 = (w >= 2) ? (S_LEN - 32 * (p + 1) + 16 * wv) : (32 * p + 16 * wv);
  const int ktdiag = row0 >> 6;
  const int ktmax  = (S_LEN - 1 - 32 * p) >> 6;
  bf16x8 qa[2];
  {
    const float* qp = Qb + (size_t)(row0 + c) * D_HEAD + quad * 8;
#pragma unroll
    for (int h = 0; h < 2; ++h) {
      f32x4 a0 = *(const f32x4*)(qp + 32 * h);
      f32x4 a1 = *(const f32x4*)(qp + 32 * h + 4);
#pragma unroll
      for (int j = 0; j < 4; ++j) {
        qa[h][j]     = (short)f2bf(a0[j] * SCALE_L2E);
        qa[h][4 + j] = (short)f2bf(a1[j] * SCALE_L2E);
      }
    }
  }
  f32x4 oa[4];
  float ls[4];
#pragma unroll
  for (int i = 0; i < 4; ++i) {
    oa[i] = (f32x4){0.f, 0.f, 0.f, 0.f};
    ls[i] = 0.f;
  }
  for (int kt = 0; kt <= ktmax; ++kt) {
    __syncthreads();
    {
      const int cp = t & 15;
      const int rg = t >> 4;
      const int col0 = cp * 4;
      const int sw = (cp >> 2) << 3;
#pragma unroll
      for (int i = 0; i < 4; ++i) {
        const int row = i * 16 + rg;
        const size_t goff = (size_t)(kt * 64 + row) * D_HEAD + col0;
        const f32x4 kv = *(const f32x4*)(Kb + goff);
        const f32x4 vv = *(const f32x4*)(Vb + goff);
        const unsigned int k01 = (rnd_bf(kv[1]) & 0xFFFF0000u) | (rnd_bf(kv[0]) >> 16);
        const unsigned int k23 = (rnd_bf(kv[3]) & 0xFFFF0000u) | (rnd_bf(kv[2]) >> 16);
        *(uint2*)&Ksh[row][col0] = make_uint2(k01, k23);
        const int kz = row ^ sw;
#pragma unroll
        for (int e = 0; e < 4; ++e)
          Vsh[col0 + e][kz] = f2bf(vv[e]);
      }
    }
    __syncthreads();
    if (kt <= ktdiag) {
      bf16x8 kf[4][2], vf[4][2];
#pragma unroll
      for (int ci = 0; ci < 4; ++ci) {
        kf[ci][0] = *(const bf16x8*)&Ksh[ci * 16 + c][quad * 8];
        kf[ci][1] = *(const bf16x8*)&Ksh[ci * 16 + c][32 + quad * 8];
        vf[ci][0] = *(const bf16x8*)&Vsh[ci * 16 + c][(quad ^ ci) * 8];
        vf[ci][1] = *(const bf16x8*)&Vsh[ci * 16 + c][32 + ((quad ^ ci) * 8)];
      }
      f32x4 sc[4];
#pragma unroll
      for (int ci = 0; ci < 4; ++ci) {
        f32x4 acc = (f32x4){-FIXM, -FIXM, -FIXM, -FIXM};
        acc = __builtin_amdgcn_mfma_f32_16x16x32_bf16(qa[0], kf[ci][0], acc, 0, 0, 0);
        acc = __builtin_amdgcn_mfma_f32_16x16x32_bf16(qa[1], kf[ci][1], acc, 0, 0, 0);
        sc[ci] = acc;
      }
      if (kt == ktdiag) {
#pragma unroll
        for (int ci = 0; ci < 4; ++ci) {
          const int gcol = kt * 64 + ci * 16 + c;
#pragma unroll
          for (int r = 0; r < 4; ++r)
            if (gcol > row0 + quad * 4 + r) sc[ci][r] = -1e30f;
        }
      }
#pragma unroll
      for (int ci = 0; ci < 4; ++ci)
#pragma unroll
        for (int r = 0; r < 4; ++r)
          sc[ci][r] = __builtin_amdgcn_exp2f(sc[ci][r]);
#pragma unroll
      for (int r = 0; r < 4; ++r)
        ls[r] += (sc[0][r] + sc[1][r]) + (sc[2][r] + sc[3][r]);
#pragma unroll
      for (int ci = 0; ci < 4; ++ci)
#pragma unroll
        for (int r = 0; r < 4; ++r) {
          const int prow = quad * 4 + r;
          Psh[w][prow][(ci * 16 + c) ^ ((prow >> 3) << 3)] = f2bf(sc[ci][r]);
        }
      const int px = (c >> 3) << 3;
      const bf16x8 pa0 = *(const bf16x8*)&Psh[w][c][(quad * 8) ^ px];
      const bf16x8 pa1 = *(const bf16x8*)&Psh[w][c][((32 + quad * 8)) ^ px];
#pragma unroll
      for (int ci = 0; ci < 4; ++ci) {
        oa[ci] = __builtin_amdgcn_mfma_f32_16x16x32_bf16(pa0, vf[ci][0], oa[ci], 0, 0, 0);
        oa[ci] = __builtin_amdgcn_mfma_f32_16x16x32_bf16(pa1, vf[ci][1], oa[ci], 0, 0, 0);
      }
    }
  }
  {
    float inv[4];
#pragma unroll
    for (int r = 0; r < 4; ++r) inv[r] = 1.0f / rowsum16(ls[r]);
#pragma unroll
    for (int ci = 0; ci < 4; ++ci)
#pragma unroll
      for (int r = 0; r < 4; ++r)
        Ob[(size_t)(row0 + quad * 4 + r) * D_HEAD + ci * 16 + c] = oa[ci][r] * inv[r];
  }
}

extern "C" void kernel_launch(void* const* d_in, const int* in_sizes, int n_in,
                              void* d_out, int out_size, void* d_ws, size_t ws_size,
                              hipStream_t stream) {
  (void)in_sizes; (void)n_in; (void)out_size;
  const float* Q = (const float*)d_in[0];
  const float* K = (const float*)d_in[1];
  const float* V = (const float*)d_in[2];
  float* O = (float*)d_out;   // d_in[3] (causal mask) computed analytically
  const size_t NEED = 2ull * 32 * S_LEN * D_HEAD * 2;  // Kb16 + Vt = 16 MB
  if (ws_size >= NEED) {
    unsigned short* Kb = (unsigned short*)d_ws;
    unsigned short* Vt = Kb + (size_t)32 * S_LEN * D_HEAD;
    prep<<<dim3(512), dim3(256), 0, stream>>>(K, V, Kb, Vt);
    fa<<<dim3(512), dim3(256), 0, stream>>>(Q, Kb, Vt, O);
  } else {
    fa_fb<<<dim3(1024), dim3(256), 0, stream>>>(Q, K, V, O);
  }
}